// Round 12
// baseline (5291.376 us; speedup 1.0000x reference)
//
#include <hip/hip_runtime.h>
#include <hip/hip_bf16.h>
#include <math.h>

#define DEV __device__ __forceinline__

typedef __attribute__((ext_vector_type(8))) short s16x8;
typedef __attribute__((ext_vector_type(4))) float f32x4;

DEV f32x4 MF(s16x8 a, s16x8 b, f32x4 c) {
    return __builtin_amdgcn_mfma_f32_16x16x32_bf16(a, b, c, 0, 0, 0);
}

// 3-term bf16 split (exact truncation residuals): x = h + m + l + O(2^-24 x)
DEV void split3(float x, unsigned short& h, unsigned short& m, unsigned short& l) {
    const unsigned u = __float_as_uint(x);
    h = (unsigned short)(u >> 16);
    const float r1 = x - __uint_as_float(u & 0xffff0000u);
    const unsigned u1 = __float_as_uint(r1);
    m = (unsigned short)(u1 >> 16);
    const float r2 = r1 - __uint_as_float(u1 & 0xffff0000u);
    l = (unsigned short)(__float_as_uint(r2) >> 16);
}

DEV void split8store(const float v[8], unsigned short* d) {
    s16x8 vh, vm, vl;
#pragma unroll
    for (int j = 0; j < 8; ++j) {
        unsigned short h, m, l;
        split3(v[j], h, m, l);
        vh[j] = (short)h; vm[j] = (short)m; vl[j] = (short)l;
    }
    *(s16x8*)(d) = vh;
    *(s16x8*)(d + 512) = vm;
    *(s16x8*)(d + 1024) = vl;
}

DEV void mfma6(f32x4& acc, s16x8 ah, s16x8 am, s16x8 al, const unsigned short* bp) {
    const s16x8 bh = *(const s16x8*)(bp);
    const s16x8 bm = *(const s16x8*)(bp + 512);
    const s16x8 bl = *(const s16x8*)(bp + 1024);
    acc = MF(ah, bh, acc);
    acc = MF(ah, bm, acc);
    acc = MF(am, bh, acc);
    acc = MF(ah, bl, acc);
    acc = MF(al, bh, acc);
    acc = MF(am, bm, acc);
}

// ---------------------------------------------------------------- transpose: [N][K] -> [K][N]
__global__ void k_tpose(const float* __restrict__ in, float* __restrict__ out, int N, int K) {
    int total = N * K;
    for (int idx = blockIdx.x * blockDim.x + threadIdx.x; idx < total; idx += gridDim.x * blockDim.x) {
        int n = idx / K, k = idx - n * K;
        out[k * N + n] = in[idx];
    }
}

// ---------------------------------------------------------------- 3-term B-frag pack, strided source
__global__ void k_wpack3(const float* __restrict__ W, unsigned short* __restrict__ WP,
                         int K, int NT, int ldw, int stride, int off) {
    const int idx = blockIdx.x * 256 + threadIdx.x;
    const int total = (K >> 5) * NT * 64;
    if (idx >= total) return;
    const int lane = idx & 63;
    const int nt = (idx >> 6) % NT;
    const int ks = idx / (64 * NT);
    const int col = nt * 16 + (lane & 15);
    const int k0 = ks * 32 + ((lane >> 4) << 3);
    const float* src = W + (size_t)col * ldw + (size_t)k0 * stride + off;
    float v[8];
#pragma unroll
    for (int j = 0; j < 8; ++j) v[j] = src[j * stride];
    split8store(v, WP + (size_t)((ks * NT + nt) * 3) * 512 + lane * 8);
}

// ---------------------------------------------------------------- conv1: [CB,20,8,8] -> a1 [CB,64,256], relu
__global__ __launch_bounds__(256) void k_conv1(const float* __restrict__ in, const float* __restrict__ w,
                                               const float* __restrict__ bias, float* __restrict__ out) {
    __shared__ __align__(16) float img[20 * 100];
    __shared__ __align__(16) float stg[16 * 260];
    const int b = blockIdx.x;
    const int t = threadIdx.x;
    for (int idx = t; idx < 2000; idx += 256) {
        int c = idx / 100, pp = idx - c * 100;
        int y = pp / 10, x = pp - y * 10;
        float v = 0.f;
        if (y >= 1 && y <= 8 && x >= 1 && x <= 8)
            v = in[((size_t)b * 20 + c) * 64 + (y - 1) * 8 + (x - 1)];
        img[idx] = v;
    }
    __syncthreads();
    const int oc = t;
    float acc[64];
    const float bz = bias[oc];
#pragma unroll
    for (int p = 0; p < 64; ++p) acc[p] = bz;
    const float* wrow = w + oc * 180;
    for (int c = 0; c < 20; ++c) {
#pragma unroll
        for (int k = 0; k < 9; ++k) {
            const int ky = k / 3, kx = k - ky * 3;
            const float wv = wrow[c * 9 + k];
            const int base = c * 100 + ky * 10 + kx;
#pragma unroll
            for (int p = 0; p < 64; ++p)
                acc[p] = fmaf(wv, img[base + p + ((p >> 3) << 1)], acc[p]);
        }
    }
#pragma unroll
    for (int cc = 0; cc < 4; ++cc) {
        __syncthreads();
#pragma unroll
        for (int p = 0; p < 16; ++p) stg[p * 260 + t] = acc[cc * 16 + p];
        __syncthreads();
        for (int idx = t; idx < 4096; idx += 256) {
            const int r = idx >> 8, c = idx & 255;
            out[((size_t)b * 64 + cc * 16 + r) * 256 + c] = fmaxf(stg[r * 260 + c], 0.f);
        }
    }
}

// ---------------------------------------------------------------- conv2 MFMA (3-term) + split-plane epilogue
__global__ __launch_bounds__(256) void k_conv2mf(const float* __restrict__ a1,
                                                 const unsigned short* __restrict__ WPC2,
                                                 const float* __restrict__ bias,
                                                 float* __restrict__ xout,
                                                 unsigned short* __restrict__ xh,
                                                 unsigned short* __restrict__ xm,
                                                 unsigned short* __restrict__ xl) {
    __shared__ __align__(16) unsigned short AhS[100 * 132];
    __shared__ __align__(16) unsigned short AmS[100 * 132];
    __shared__ __align__(16) unsigned short AlS[100 * 132];
    const int b = blockIdx.x, t = threadIdx.x;
    const int wv = t >> 6, lane = t & 63;
    f32x4 acc[16];
#pragma unroll
    for (int nt = 0; nt < 16; ++nt) acc[nt] = (f32x4){0.f, 0.f, 0.f, 0.f};
    const int pl = lane & 15;
    const int py = pl >> 3, px = pl & 7;
    const int akoff = (lane >> 4) << 3;
    for (int h = 0; h < 2; ++h) {
        __syncthreads();
        for (int idx = t; idx < 12800; idx += 256) {
            const int pr = idx >> 7, c = idx & 127;
            const int Y = pr / 10, X = pr - Y * 10;
            float v = 0.f;
            if (Y >= 1 && Y <= 8 && X >= 1 && X <= 8)
                v = a1[((size_t)b * 64 + (Y - 1) * 8 + X - 1) * 256 + h * 128 + c];
            unsigned short hh, mm, ll;
            split3(v, hh, mm, ll);
            AhS[pr * 132 + c] = hh;
            AmS[pr * 132 + c] = mm;
            AlS[pr * 132 + c] = ll;
        }
        __syncthreads();
#pragma unroll
        for (int tap = 0; tap < 9; ++tap) {
            const int dy = tap / 3, dx = tap - dy * 3;
            const int prow = (wv * 2 + py + dy) * 10 + px + dx;
            const unsigned short* arh = AhS + prow * 132 + akoff;
            const unsigned short* arm = AmS + prow * 132 + akoff;
            const unsigned short* arl = AlS + prow * 132 + akoff;
#pragma unroll
            for (int ks = 0; ks < 4; ++ks) {
                const s16x8 ah = *(const s16x8*)(arh + ks * 32);
                const s16x8 am = *(const s16x8*)(arm + ks * 32);
                const s16x8 al = *(const s16x8*)(arl + ks * 32);
                const unsigned short* bp = WPC2 + (size_t)(tap * 128 + (h * 4 + ks) * 16) * 1536 + lane * 8;
#pragma unroll
                for (int nt = 0; nt < 16; ++nt) {
                    mfma6(acc[nt], ah, am, al, bp + nt * 1536);
                }
            }
        }
    }
    const int prow0 = wv * 16 + ((lane >> 4) << 2);
    const int ccol = lane & 15;
#pragma unroll
    for (int nt = 0; nt < 16; ++nt) {
        const float bz = bias[nt * 16 + ccol];
#pragma unroll
        for (int i = 0; i < 4; ++i) {
            const float v = fmaxf(acc[nt][i] + bz, 0.f);
            const size_t o = ((size_t)b * 64 + prow0 + i) * 256 + nt * 16 + ccol;
            xout[o] = v;
            unsigned short hh, mm, ll;
            split3(v, hh, mm, ll);
            xh[o] = hh;
            xm[o] = mm;
            xl[o] = ll;
        }
    }
}

// ---------------------------------------------------------------- attention core per (b, head): qkv fp32 in, o splits out
__global__ __launch_bounds__(512) void k_attn2(const float* __restrict__ qkv,
                                               unsigned short* __restrict__ oh, unsigned short* __restrict__ om,
                                               unsigned short* __restrict__ ol) {
    __shared__ __align__(16) float qs[64 * 65];  // q, then reused for P
    __shared__ __align__(16) float ks[64 * 68];  // k, then reused for output staging
    __shared__ __align__(16) float vs[64 * 68];
    __shared__ float pmax[8 * 64];
    __shared__ float psum[8 * 64];
    const int b = blockIdx.x, h = blockIdx.y;
    const int t = threadIdx.x;
    for (int idx = t; idx < 1024; idx += 512) {
        const int rr = idx >> 4, cc = (idx & 15) * 4;
        const float* src = qkv + ((size_t)b * 64 + rr) * 768 + h * 64 + cc;
        const float4 q4 = *(const float4*)(src);
        const float4 k4 = *(const float4*)(src + 256);
        const float4 v4 = *(const float4*)(src + 512);
        qs[rr * 65 + cc + 0] = q4.x; qs[rr * 65 + cc + 1] = q4.y;
        qs[rr * 65 + cc + 2] = q4.z; qs[rr * 65 + cc + 3] = q4.w;
        *(float4*)(ks + rr * 68 + cc) = k4;
        *(float4*)(vs + rr * 68 + cc) = v4;
    }
    __syncthreads();
    const int r = t & 63;
    const int cg = t >> 6;
    float sc[8];
#pragma unroll
    for (int j = 0; j < 8; ++j) sc[j] = 0.f;
    for (int kk = 0; kk < 64; kk += 4) {
        float qv[4];
#pragma unroll
        for (int i = 0; i < 4; ++i) qv[i] = qs[r * 65 + kk + i];
#pragma unroll
        for (int j = 0; j < 8; ++j) {
            const float4 kv = *(const float4*)(ks + (cg * 8 + j) * 68 + kk);
            sc[j] = fmaf(qv[0], kv.x, sc[j]); sc[j] = fmaf(qv[1], kv.y, sc[j]);
            sc[j] = fmaf(qv[2], kv.z, sc[j]); sc[j] = fmaf(qv[3], kv.w, sc[j]);
        }
    }
    float pm = -1e30f;
#pragma unroll
    for (int j = 0; j < 8; ++j) { sc[j] *= 0.125f; pm = fmaxf(pm, sc[j]); }
    pmax[cg * 64 + r] = pm;
    __syncthreads();
    float m = pmax[r];
#pragma unroll
    for (int i = 1; i < 8; ++i) m = fmaxf(m, pmax[i * 64 + r]);
    float pe[8], ps = 0.f;
#pragma unroll
    for (int j = 0; j < 8; ++j) { pe[j] = __expf(sc[j] - m); ps += pe[j]; }
    psum[cg * 64 + r] = ps;
    __syncthreads();
    float den = psum[r];
#pragma unroll
    for (int i = 1; i < 8; ++i) den += psum[i * 64 + r];
    const float rden = 1.f / den;
#pragma unroll
    for (int j = 0; j < 8; ++j) qs[r * 65 + cg * 8 + j] = pe[j] * rden;  // P overwrites q
    __syncthreads();
    float oa[8];
#pragma unroll
    for (int j = 0; j < 8; ++j) oa[j] = 0.f;
    for (int c = 0; c < 64; ++c) {
        const float pv = qs[r * 65 + c];
        const float4 v0 = *(const float4*)(vs + c * 68 + cg * 8);
        const float4 v1 = *(const float4*)(vs + c * 68 + cg * 8 + 4);
        oa[0] = fmaf(pv, v0.x, oa[0]); oa[1] = fmaf(pv, v0.y, oa[1]);
        oa[2] = fmaf(pv, v0.z, oa[2]); oa[3] = fmaf(pv, v0.w, oa[3]);
        oa[4] = fmaf(pv, v1.x, oa[4]); oa[5] = fmaf(pv, v1.y, oa[5]);
        oa[6] = fmaf(pv, v1.z, oa[6]); oa[7] = fmaf(pv, v1.w, oa[7]);
    }
#pragma unroll
    for (int j = 0; j < 8; ++j) ks[r * 68 + cg * 8 + j] = oa[j];
    __syncthreads();
    for (int idx = t; idx < 4096; idx += 512) {
        const int rr = idx >> 6, dd = idx & 63;
        const float v = ks[rr * 68 + dd];
        unsigned short hh, mm, ll;
        split3(v, hh, mm, ll);
        const size_t o = ((size_t)b * 64 + rr) * 256 + h * 64 + dd;
        oh[o] = hh;
        om[o] = mm;
        ol[o] = ll;
    }
}

// ---------------------------------------------------------------- MFMA GEMM 64-row (be1/be2, split-K)
__global__ __launch_bounds__(256) void k_gemm_mf(
    const unsigned short* __restrict__ Ah, const unsigned short* __restrict__ Am,
    const unsigned short* __restrict__ Al,
    const unsigned short* __restrict__ WP, const float* __restrict__ bias,
    float* __restrict__ Cf, unsigned short* __restrict__ Ch, unsigned short* __restrict__ Cm,
    unsigned short* __restrict__ Cl,
    int M, int N, int K, int kChunk, int relu) {
    const int t = threadIdx.x;
    const int wv = t >> 6, lane = t & 63;
    const int row0 = blockIdx.x * 64 + wv * 16;
    const int col0 = blockIdx.y * 64;
    const int NT = N >> 4;
    const int k0 = blockIdx.z * kChunk;
    const int nks = kChunk >> 5;
    f32x4 acc[4];
#pragma unroll
    for (int nt = 0; nt < 4; ++nt) acc[nt] = (f32x4){0.f, 0.f, 0.f, 0.f};
    const int arow = row0 + (lane & 15);
    const size_t aoff = (size_t)arow * K + k0 + ((lane >> 4) << 3);
    const unsigned short* aph = Ah + aoff;
    const unsigned short* apm = Am + aoff;
    const unsigned short* apl = Al + aoff;
    const unsigned short* bp = WP + ((size_t)((k0 >> 5) * NT + (col0 >> 4))) * 1536 + lane * 8;
    const size_t bstride = (size_t)NT * 1536;
    for (int ks = 0; ks < nks; ++ks) {
        const s16x8 ah = *(const s16x8*)aph;
        const s16x8 am = *(const s16x8*)apm;
        const s16x8 al = *(const s16x8*)apl;
        aph += 32; apm += 32; apl += 32;
#pragma unroll
        for (int nt = 0; nt < 4; ++nt) {
            mfma6(acc[nt], ah, am, al, bp + nt * 1536);
        }
        bp += bstride;
    }
    const int crow = row0 + ((lane >> 4) << 2);
    const int ccol = col0 + (lane & 15);
    float bz[4];
#pragma unroll
    for (int nt = 0; nt < 4; ++nt) bz[nt] = bias ? bias[ccol + nt * 16] : 0.f;
    if (Ch) {
#pragma unroll
        for (int nt = 0; nt < 4; ++nt) {
#pragma unroll
            for (int i = 0; i < 4; ++i) {
                float v = acc[nt][i] + bz[nt];
                if (relu) v = fmaxf(v, 0.f);
                unsigned short hh, mm, ll;
                split3(v, hh, mm, ll);
                const size_t o = (size_t)(crow + i) * N + ccol + nt * 16;
                Ch[o] = hh;
                Cm[o] = mm;
                Cl[o] = ll;
            }
        }
    } else {
        float* base = Cf + (size_t)blockIdx.z * M * N;
#pragma unroll
        for (int nt = 0; nt < 4; ++nt) {
#pragma unroll
            for (int i = 0; i < 4; ++i) {
                float v = acc[nt][i] + bz[nt];
                if (relu) v = fmaxf(v, 0.f);
                base[(size_t)(crow + i) * N + ccol + nt * 16] = v;
            }
        }
    }
}

// ---------------------------------------------------------------- MFMA GEMM 128-row: 32 rows/wave, 48 MFMA / 18 loads per ks
__global__ __launch_bounds__(256) void k_gemm_mf128(
    const unsigned short* __restrict__ Ah, const unsigned short* __restrict__ Am,
    const unsigned short* __restrict__ Al,
    const unsigned short* __restrict__ WP, const float* __restrict__ bias,
    float* __restrict__ Cf, unsigned short* __restrict__ Ch, unsigned short* __restrict__ Cm,
    unsigned short* __restrict__ Cl,
    int M, int N, int K, int relu) {
    const int t = threadIdx.x;
    const int wv = t >> 6, lane = t & 63;
    const int row0 = blockIdx.x * 128 + wv * 32;
    const int col0 = blockIdx.y * 64;
    const int NT = N >> 4;
    const int nks = K >> 5;
    f32x4 acc0[4], acc1[4];
#pragma unroll
    for (int nt = 0; nt < 4; ++nt) {
        acc0[nt] = (f32x4){0.f, 0.f, 0.f, 0.f};
        acc1[nt] = (f32x4){0.f, 0.f, 0.f, 0.f};
    }
    const size_t aoff0 = (size_t)(row0 + (lane & 15)) * K + ((lane >> 4) << 3);
    const size_t aoff1 = aoff0 + (size_t)16 * K;
    const unsigned short* bp = WP + (size_t)(col0 >> 4) * 1536 + lane * 8;
    const size_t bstride = (size_t)NT * 1536;
    for (int ks = 0; ks < nks; ++ks) {
        const size_t ao = ks * 32;
        const s16x8 a0h = *(const s16x8*)(Ah + aoff0 + ao);
        const s16x8 a0m = *(const s16x8*)(Am + aoff0 + ao);
        const s16x8 a0l = *(const s16x8*)(Al + aoff0 + ao);
        const s16x8 a1h = *(const s16x8*)(Ah + aoff1 + ao);
        const s16x8 a1m = *(const s16x8*)(Am + aoff1 + ao);
        const s16x8 a1l = *(const s16x8*)(Al + aoff1 + ao);
#pragma unroll
        for (int nt = 0; nt < 4; ++nt) {
            const unsigned short* bb = bp + nt * 1536;
            const s16x8 bh = *(const s16x8*)(bb);
            const s16x8 bm = *(const s16x8*)(bb + 512);
            const s16x8 bl = *(const s16x8*)(bb + 1024);
            acc0[nt] = MF(a0h, bh, acc0[nt]);
            acc0[nt] = MF(a0h, bm, acc0[nt]);
            acc0[nt] = MF(a0m, bh, acc0[nt]);
            acc0[nt] = MF(a0h, bl, acc0[nt]);
            acc0[nt] = MF(a0l, bh, acc0[nt]);
            acc0[nt] = MF(a0m, bm, acc0[nt]);
            acc1[nt] = MF(a1h, bh, acc1[nt]);
            acc1[nt] = MF(a1h, bm, acc1[nt]);
            acc1[nt] = MF(a1m, bh, acc1[nt]);
            acc1[nt] = MF(a1h, bl, acc1[nt]);
            acc1[nt] = MF(a1l, bh, acc1[nt]);
            acc1[nt] = MF(a1m, bm, acc1[nt]);
        }
        bp += bstride;
    }
    const int crow0 = row0 + ((lane >> 4) << 2);
    const int ccol = col0 + (lane & 15);
    float bz[4];
#pragma unroll
    for (int nt = 0; nt < 4; ++nt) bz[nt] = bias ? bias[ccol + nt * 16] : 0.f;
#pragma unroll
    for (int half = 0; half < 2; ++half) {
        const int crow = crow0 + half * 16;
        f32x4* ac = half ? acc1 : acc0;
        if (Ch) {
#pragma unroll
            for (int nt = 0; nt < 4; ++nt) {
#pragma unroll
                for (int i = 0; i < 4; ++i) {
                    float v = ac[nt][i] + bz[nt];
                    if (relu) v = fmaxf(v, 0.f);
                    unsigned short hh, mm, ll;
                    split3(v, hh, mm, ll);
                    const size_t o = (size_t)(crow + i) * N + ccol + nt * 16;
                    Ch[o] = hh;
                    Cm[o] = mm;
                    Cl[o] = ll;
                }
            }
        } else {
#pragma unroll
            for (int nt = 0; nt < 4; ++nt) {
#pragma unroll
                for (int i = 0; i < 4; ++i) {
                    float v = ac[nt][i] + bz[nt];
                    if (relu) v = fmaxf(v, 0.f);
                    Cf[(size_t)(crow + i) * N + ccol + nt * 16] = v;
                }
            }
        }
    }
}

// ---------------------------------------------------------------- x = LN(x + add); writes fp32 + 3-plane split
__global__ __launch_bounds__(256) void k_ln_add(float* __restrict__ x, const float* __restrict__ add,
                                                const float* __restrict__ g, const float* __restrict__ bta,
                                                unsigned short* __restrict__ sh, unsigned short* __restrict__ sm,
                                                unsigned short* __restrict__ sl) {
    const int t = threadIdx.x;
    const size_t r = (size_t)blockIdx.x * 4 + (t >> 6);
    const int lane = t & 63;
    float4 xv = *(const float4*)(x + r * 256 + lane * 4);
    const float4 av = *(const float4*)(add + r * 256 + lane * 4);
    const float4 v = make_float4(xv.x + av.x, xv.y + av.y, xv.z + av.z, xv.w + av.w);
    float s = v.x + v.y + v.z + v.w;
    float ss = fmaf(v.x, v.x, fmaf(v.y, v.y, fmaf(v.z, v.z, v.w * v.w)));
#pragma unroll
    for (int m = 32; m; m >>= 1) { s += __shfl_xor(s, m); ss += __shfl_xor(ss, m); }
    const float mean = s * (1.f / 256.f);
    const float var = ss * (1.f / 256.f) - mean * mean;
    const float rstd = rsqrtf(var + 1e-5f);
    const float4 g4 = *(const float4*)(g + lane * 4);
    const float4 b4 = *(const float4*)(bta + lane * 4);
    float4 ov;
    ov.x = (v.x - mean) * rstd * g4.x + b4.x;
    ov.y = (v.y - mean) * rstd * g4.y + b4.y;
    ov.z = (v.z - mean) * rstd * g4.z + b4.z;
    ov.w = (v.w - mean) * rstd * g4.w + b4.w;
    *(float4*)(x + r * 256 + lane * 4) = ov;
    const float vv[4] = {ov.x, ov.y, ov.z, ov.w};
    unsigned short hh[4], mm[4], ll[4];
#pragma unroll
    for (int j = 0; j < 4; ++j) split3(vv[j], hh[j], mm[j], ll[j]);
    *(ushort4*)(sh + r * 256 + lane * 4) = make_ushort4(hh[0], hh[1], hh[2], hh[3]);
    *(ushort4*)(sm + r * 256 + lane * 4) = make_ushort4(mm[0], mm[1], mm[2], mm[3]);
    *(ushort4*)(sl + r * 256 + lane * 4) = make_ushort4(ll[0], ll[1], ll[2], ll[3]);
}

// ---------------------------------------------------------------- be1 split-K reduce + bias + relu -> 3-plane split
__global__ void k_be1_reduce(const float* __restrict__ parts, const float* __restrict__ bias,
                             unsigned short* __restrict__ oh, unsigned short* __restrict__ om,
                             unsigned short* __restrict__ ol, int n) {
    const int idx = blockIdx.x * blockDim.x + threadIdx.x;
    if (idx < n) {
        float s = bias[idx & 255];
#pragma unroll
        for (int p = 0; p < 8; ++p) s += parts[(size_t)p * n + idx];
        s = fmaxf(s, 0.f);
        unsigned short hh, mm, ll;
        split3(s, hh, mm, ll);
        oh[idx] = hh;
        om[idx] = mm;
        ol[idx] = ll;
    }
}

// ================================================================ HRM recurrence, MFMA — fp32 z in LDS, split at A-load
// LDS: 4 fp32 buffers [16][260] = 66.5 KB -> 2 blocks/CU (vs 115 KB / 1 block before).
DEV void loadsplitA(const float* z, int kl, int lane, s16x8& ah, s16x8& am, s16x8& al) {
    const int row = lane & 15;
    const int k0 = kl * 32 + ((lane >> 4) << 3);
    const float4 p = *(const float4*)(z + row * 260 + k0);
    const float4 q = *(const float4*)(z + row * 260 + k0 + 4);
    const float v[8] = {p.x, p.y, p.z, p.w, q.x, q.y, q.z, q.w};
#pragma unroll
    for (int j = 0; j < 8; ++j) {
        unsigned short h, m, l;
        split3(v[j], h, m, l);
        ah[j] = (short)h; am[j] = (short)m; al[j] = (short)l;
    }
}

DEV void rungemm(f32x4& a0, f32x4& a1, const unsigned short* __restrict__ WP, int KS,
                 const float* z0, const float* z1, const float* z2,
                 int wv, int lane) {
    for (int ks = 0; ks < KS; ++ks) {
        const float* za = (ks < 8) ? z0 : ((ks < 16) ? z1 : z2);
        s16x8 ah, am, al;
        loadsplitA(za, ks & 7, lane, ah, am, al);
        const unsigned short* bp = WP + (size_t)((ks * 16 + wv * 2) * 3) * 512 + lane * 8;
        mfma6(a0, ah, am, al, bp);
        mfma6(a1, ah, am, al, bp + 1536);
    }
}

DEV void storeC(f32x4 a0, f32x4 a1, const float* __restrict__ bias, float* dst, int wv, int lane) {
    const int rb = (lane >> 4) * 4;
    const int c0 = wv * 32 + (lane & 15);
    const float bz0 = bias[c0];
    const float bz1 = bias[c0 + 16];
    dst[(rb + 0) * 260 + c0] = fmaxf(a0[0] + bz0, 0.f);
    dst[(rb + 1) * 260 + c0] = fmaxf(a0[1] + bz0, 0.f);
    dst[(rb + 2) * 260 + c0] = fmaxf(a0[2] + bz0, 0.f);
    dst[(rb + 3) * 260 + c0] = fmaxf(a0[3] + bz0, 0.f);
    dst[(rb + 0) * 260 + c0 + 16] = fmaxf(a1[0] + bz1, 0.f);
    dst[(rb + 1) * 260 + c0 + 16] = fmaxf(a1[1] + bz1, 0.f);
    dst[(rb + 2) * 260 + c0 + 16] = fmaxf(a1[2] + bz1, 0.f);
    dst[(rb + 3) * 260 + c0 + 16] = fmaxf(a1[3] + bz1, 0.f);
}

DEV void lnpass(float* zbuf, const float* __restrict__ g, const float* __restrict__ bb, int t) {
    const int row = 2 * (t >> 6) + ((t & 63) >> 5);
    const int c0 = (t & 31) * 8;
    float* s = zbuf + row * 260 + c0;
    const float4 x0 = *(const float4*)s;
    const float4 x1 = *(const float4*)(s + 4);
    float sum = x0.x + x0.y + x0.z + x0.w + x1.x + x1.y + x1.z + x1.w;
    float sq = fmaf(x0.x, x0.x, fmaf(x0.y, x0.y, fmaf(x0.z, x0.z, x0.w * x0.w)));
    sq = fmaf(x1.x, x1.x, fmaf(x1.y, x1.y, fmaf(x1.z, x1.z, fmaf(x1.w, x1.w, sq))));
#pragma unroll
    for (int m = 16; m; m >>= 1) { sum += __shfl_xor(sum, m); sq += __shfl_xor(sq, m); }
    const float mean = sum * (1.f / 256.f);
    const float var = sq * (1.f / 256.f) - mean * mean;
    const float rstd = rsqrtf(var + 1e-5f);
    const float4 g0 = *(const float4*)(g + c0);
    const float4 g1 = *(const float4*)(g + c0 + 4);
    const float4 b0 = *(const float4*)(bb + c0);
    const float4 b1 = *(const float4*)(bb + c0 + 4);
    float4 o0, o1;
    o0.x = (x0.x - mean) * rstd * g0.x + b0.x;
    o0.y = (x0.y - mean) * rstd * g0.y + b0.y;
    o0.z = (x0.z - mean) * rstd * g0.z + b0.z;
    o0.w = (x0.w - mean) * rstd * g0.w + b0.w;
    o1.x = (x1.x - mean) * rstd * g1.x + b1.x;
    o1.y = (x1.y - mean) * rstd * g1.y + b1.y;
    o1.z = (x1.z - mean) * rstd * g1.z + b1.z;
    o1.w = (x1.w - mean) * rstd * g1.w + b1.w;
    *(float4*)s = o0;
    *(float4*)(s + 4) = o1;
}

__global__ __launch_bounds__(512, 2) void k_hrm(const float* __restrict__ be,
        const unsigned short* __restrict__ L1P, const float* __restrict__ L1b,
        const unsigned short* __restrict__ L2P, const float* __restrict__ L2b,
        const float* __restrict__ Lg, const float* __restrict__ Lbt,
        const unsigned short* __restrict__ H1P, const float* __restrict__ H1b,
        const unsigned short* __restrict__ H2P, const float* __restrict__ H2b,
        const float* __restrict__ Hg, const float* __restrict__ Hbt,
        const unsigned short* __restrict__ v1P, const float* __restrict__ v1b,
        const float* __restrict__ v2T, const float* __restrict__ v2b,
        float* __restrict__ out) {
    __shared__ __align__(16) float zL[16 * 260];
    __shared__ __align__(16) float zH[16 * 260];
    __shared__ __align__(16) float beS[16 * 260];
    __shared__ __align__(16) float h1[16 * 260];
    const int t = threadIdx.x;
    const int b0 = blockIdx.x * 16;
    const int wv = t >> 6, lane = t & 63;
    for (int i = t; i < 4160; i += 512) { zL[i] = 0.f; zH[i] = 0.f; }
    for (int idx = t; idx < 2048; idx += 512) {
        const int r = idx >> 7, c = idx & 127;
        const float2 v = *(const float2*)(be + (size_t)(b0 + r) * 256 + c * 2);
        beS[r * 260 + c * 2] = v.x;
        beS[r * 260 + c * 2 + 1] = v.y;
    }
    __syncthreads();
    const f32x4 zero4 = {0.f, 0.f, 0.f, 0.f};
    for (int it = 0; it < 64; ++it) {
        // h1 = relu(cat(zL,zH,be) @ L1^T + b)
        f32x4 a0 = zero4, a1 = zero4;
        rungemm(a0, a1, L1P, 24, zL, zH, beS, wv, lane);
        storeC(a0, a1, L1b, h1, wv, lane);
        __syncthreads();
        // zL = LN(relu(h1 @ L2^T + b))
        a0 = zero4; a1 = zero4;
        rungemm(a0, a1, L2P, 8, h1, h1, h1, wv, lane);
        storeC(a0, a1, L2b, zL, wv, lane);
        __syncthreads();
        lnpass(zL, Lg, Lbt, t);
        __syncthreads();
        if (((it + 1) & 7) == 0) {
            a0 = zero4; a1 = zero4;
            rungemm(a0, a1, H1P, 16, zH, zL, zL, wv, lane);
            storeC(a0, a1, H1b, h1, wv, lane);
            __syncthreads();
            a0 = zero4; a1 = zero4;
            rungemm(a0, a1, H2P, 8, h1, h1, h1, wv, lane);
            storeC(a0, a1, H2b, zH, wv, lane);
            __syncthreads();
            lnpass(zH, Hg, Hbt, t);
            __syncthreads();
        }
    }
    // head: out = relu(zH @ v1^T + b) @ v2^T + b
    f32x4 a0 = zero4, a1 = zero4;
    rungemm(a0, a1, v1P, 8, zH, zH, zH, wv, lane);
    storeC(a0, a1, v1b, h1, wv, lane);
    __syncthreads();
    for (int idx = t; idx < 2048; idx += 512) {
        const int r = idx >> 7, oo = idx & 127;
        float s = v2b[oo];
        for (int kk = 0; kk < 256; kk += 4) {
            const float4 c4 = *(const float4*)(&h1[r * 260 + kk]);
            s = fmaf(c4.x, v2T[(kk + 0) * 128 + oo], s);
            s = fmaf(c4.y, v2T[(kk + 1) * 128 + oo], s);
            s = fmaf(c4.z, v2T[(kk + 2) * 128 + oo], s);
            s = fmaf(c4.w, v2T[(kk + 3) * 128 + oo], s);
        }
        out[(size_t)(b0 + r) * 128 + oo] = s;
    }
}

// ================================================================ launch
extern "C" void kernel_launch(void* const* d_in, const int* in_sizes, int n_in,
                              void* d_out, int out_size, void* d_ws, size_t ws_size,
                              hipStream_t stream) {
    const float* bitplanes  = (const float*)d_in[0];
    const float* conv1_w    = (const float*)d_in[1];
    const float* conv1_b    = (const float*)d_in[2];
    const float* conv2_w    = (const float*)d_in[3];
    const float* conv2_b    = (const float*)d_in[4];
    const float* in_proj_w  = (const float*)d_in[5];
    const float* in_proj_b  = (const float*)d_in[6];
    const float* out_proj_w = (const float*)d_in[7];
    const float* out_proj_b = (const float*)d_in[8];
    const float* ln1_g      = (const float*)d_in[9];
    const float* ln1_b      = (const float*)d_in[10];
    const float* ff1_w      = (const float*)d_in[11];
    const float* ff1_b      = (const float*)d_in[12];
    const float* ff2_w      = (const float*)d_in[13];
    const float* ff2_b      = (const float*)d_in[14];
    const float* ln2_g      = (const float*)d_in[15];
    const float* ln2_b      = (const float*)d_in[16];
    const float* be1_w      = (const float*)d_in[17];
    const float* be1_b      = (const float*)d_in[18];
    const float* be2_w      = (const float*)d_in[19];
    const float* be2_b      = (const float*)d_in[20];
    const float* L1_w       = (const float*)d_in[21];
    const float* L1_b       = (const float*)d_in[22];
    const float* L2_w       = (const float*)d_in[23];
    const float* L2_b       = (const float*)d_in[24];
    const float* Lln_g      = (const float*)d_in[25];
    const float* Lln_b      = (const float*)d_in[26];
    const float* H1_w       = (const float*)d_in[27];
    const float* H1_b       = (const float*)d_in[28];
    const float* H2_w       = (const float*)d_in[29];
    const float* H2_b       = (const float*)d_in[30];
    const float* Hln_g      = (const float*)d_in[31];
    const float* Hln_b      = (const float*)d_in[32];
    const float* v1_w       = (const float*)d_in[33];
    const float* v1_b       = (const float*)d_in[34];
    const float* v2_w       = (const float*)d_in[35];
    const float* v2_b       = (const float*)d_in[36];

    // per-chunk floats = CB*106880; persistent tail = 9,404,416 floats
    const size_t persist = 9404416ull;
    int CB = 64;
    for (int c = 2048; c >= 64; c >>= 1) {
        size_t needBytes = ((size_t)c * 106880ull + persist) * 4ull;
        if (needBytes <= ws_size) { CB = c; break; }
    }
    const int NCH = 2048 / CB;

    float* ws = (float*)d_ws;
    float* a1buf = ws;                                  // CB*16384 fp32
    float* xbuf  = a1buf + (size_t)CB * 16384;          // CB*16384 fp32
    float* sbuf  = xbuf + (size_t)CB * 16384;           // CB*24576 fl = 3 bf16 planes CB*64*256
    float* tbuf  = sbuf + (size_t)CB * 24576;           // CB*49152 fl (qkv fp32 / ff1 planes / be1 parts)
    float* bemf  = tbuf + (size_t)CB * 49152;           // CB*384 fl = 3 bf16 planes CB*256
    float* wpQf  = bemf + (size_t)CB * 384;             // 294,912 (in_proj 3-term pack)
    float* v2T   = wpQf + 294912;                       // 32,768
    float* L1Pf  = v2T + 32768;                         // 294,912
    float* L2Pf  = L1Pf + 294912;                       // 98,304
    float* H1Pf  = L2Pf + 98304;                        // 196,608
    float* H2Pf  = H1Pf + 196608;                       // 98,304
    float* v1Pf  = H2Pf + 98304;                        // 98,304
    float* beB   = v1Pf + 98304;                        // 524,288
    float* wpOf  = beB + 524288;                        // 98,304
    float* wpF1f = wpOf + 98304;                        // 196,608
    float* wpF2f = wpF1f + 196608;                      // 196,608
    float* wpB1f = wpF2f + 196608;                      // 6,291,456
    float* wpB2f = wpB1f + 6291456;                     // 98,304
    float* wpC2f = wpB2f + 98304;                       // 884,736

    unsigned short* soh = (unsigned short*)sbuf;
    unsigned short* som = soh + (size_t)CB * 16384;
    unsigned short* sol = som + (size_t)CB * 16384;
    unsigned short* tbh = (unsigned short*)tbuf;
    unsigned short* tbm = tbh + (size_t)CB * 32768;
    unsigned short* tbl = tbm + (size_t)CB * 32768;
    unsigned short* bemh = (unsigned short*)bemf;
    unsigned short* bemm = bemh + (size_t)CB * 256;
    unsigned short* beml = bemm + (size_t)CB * 256;
    unsigned short* wpQ = (unsigned short*)wpQf;
    unsigned short* L1P = (unsigned short*)L1Pf;
    unsigned short* L2P = (unsigned short*)L2Pf;
    unsigned short* H1P = (unsigned short*)H1Pf;
    unsigned short* H2P = (unsigned short*)H2Pf;
    unsigned short* v1P = (unsigned short*)v1Pf;
    unsigned short* wpO = (unsigned short*)wpOf;
    unsigned short* wpF1 = (unsigned short*)wpF1f;
    unsigned short* wpF2 = (unsigned short*)wpF2f;
    unsigned short* wpB1 = (unsigned short*)wpB1f;
    unsigned short* wpB2 = (unsigned short*)wpB2f;
    unsigned short* wpC2 = (unsigned short*)wpC2f;

    // weight prep (once) — all packs 3-term
    k_tpose<<<64, 256, 0, stream>>>(v2_w, v2T, 128, 256);
    k_wpack3<<<96, 256, 0, stream>>>(in_proj_w, wpQ, 256, 48, 256, 1, 0);
    k_wpack3<<<96, 256, 0, stream>>>(L1_w, L1P, 768, 16, 768, 1, 0);
    k_wpack3<<<32, 256, 0, stream>>>(L2_w, L2P, 256, 16, 256, 1, 0);
    k_wpack3<<<64, 256, 0, stream>>>(H1_w, H1P, 512, 16, 512, 1, 0);
    k_wpack3<<<32, 256, 0, stream>>>(H2_w, H2P, 256, 16, 256, 1, 0);
    k_wpack3<<<32, 256, 0, stream>>>(v1_w, v1P, 256, 16, 256, 1, 0);
    k_wpack3<<<32, 256, 0, stream>>>(out_proj_w, wpO, 256, 16, 256, 1, 0);
    k_wpack3<<<64, 256, 0, stream>>>(ff1_w, wpF1, 256, 32, 256, 1, 0);
    k_wpack3<<<64, 256, 0, stream>>>(ff2_w, wpF2, 512, 16, 512, 1, 0);
    k_wpack3<<<2048, 256, 0, stream>>>(be1_w, wpB1, 16384, 16, 16384, 1, 0);
    k_wpack3<<<32, 256, 0, stream>>>(be2_w, wpB2, 256, 16, 256, 1, 0);
    for (int tap = 0; tap < 9; ++tap)
        k_wpack3<<<32, 256, 0, stream>>>(conv2_w, wpC2 + (size_t)tap * 196608, 256, 16, 2304, 9, tap);

    for (int ch = 0; ch < NCH; ++ch) {
        const float* bp_c = bitplanes + (size_t)ch * CB * 20 * 64;
        // conv encoder (conv2 emits x fp32 + split planes)
        k_conv1<<<CB, 256, 0, stream>>>(bp_c, conv1_w, conv1_b, a1buf);
        k_conv2mf<<<CB, 256, 0, stream>>>(a1buf, wpC2, conv2_b, xbuf, soh, som, sol);
        // qkv projection (wide MFMA GEMM) then attention core
        k_gemm_mf128<<<dim3(CB / 2, 12), 256, 0, stream>>>(soh, som, sol, wpQ, in_proj_b,
                                                           tbuf, nullptr, nullptr, nullptr,
                                                           CB * 64, 768, 256, 0);
        k_attn2<<<dim3(CB, 4), 512, 0, stream>>>(tbuf, soh, som, sol);
        k_gemm_mf128<<<dim3(CB / 2, 4), 256, 0, stream>>>(soh, som, sol, wpO, out_proj_b,
                                                          a1buf, nullptr, nullptr, nullptr,
                                                          CB * 64, 256, 256, 0);
        k_ln_add<<<CB * 16, 256, 0, stream>>>(xbuf, a1buf, ln1_g, ln1_b, soh, som, sol);
        k_gemm_mf128<<<dim3(CB / 2, 8), 256, 0, stream>>>(soh, som, sol, wpF1, ff1_b,
                                                          nullptr, tbh, tbm, tbl,
                                                          CB * 64, 512, 256, 1);
        k_gemm_mf128<<<dim3(CB / 2, 4), 256, 0, stream>>>(tbh, tbm, tbl, wpF2, ff2_b,
                                                          a1buf, nullptr, nullptr, nullptr,
                                                          CB * 64, 256, 512, 0);
        k_ln_add<<<CB * 16, 256, 0, stream>>>(xbuf, a1buf, ln2_g, ln2_b, soh, som, sol);
        // board embedding: be = relu(relu(xf@be1^T+b)@be2^T+b)
        k_gemm_mf<<<dim3(CB / 64, 4, 8), 256, 0, stream>>>(soh, som, sol, wpB1, nullptr,
                                                           tbuf, nullptr, nullptr, nullptr,
                                                           CB, 256, 16384, 2048, 0);
        k_be1_reduce<<<CB, 256, 0, stream>>>(tbuf, be1_b, bemh, bemm, beml, CB * 256);
        k_gemm_mf<<<dim3(CB / 64, 4, 1), 256, 0, stream>>>(bemh, bemm, beml, wpB2, be2_b,
                                                           beB + (size_t)ch * CB * 256, nullptr, nullptr, nullptr,
                                                           CB, 256, 256, 256, 1);
    }

    // HRM recurrence + head (MFMA, 128 blocks x 16 rows, fp32-z LDS)
    k_hrm<<<128, 512, 0, stream>>>(beB, L1P, L1_b, L2P, L2_b, Lln_g, Lln_b,
                                   H1P, H1_b, H2P, H2_b, Hln_g, Hln_b,
                                   v1P, v1_b, v2T, v2_b, (float*)d_out);
}

// Round 13
// 5147.618 us; speedup vs baseline: 1.0279x; 1.0279x over previous
//
#include <hip/hip_runtime.h>
#include <hip/hip_bf16.h>
#include <math.h>

#define DEV __device__ __forceinline__

typedef __attribute__((ext_vector_type(8))) short s16x8;
typedef __attribute__((ext_vector_type(4))) float f32x4;

DEV f32x4 MF(s16x8 a, s16x8 b, f32x4 c) {
    return __builtin_amdgcn_mfma_f32_16x16x32_bf16(a, b, c, 0, 0, 0);
}

// 3-term bf16 split (exact truncation residuals): x = h + m + l + O(2^-24 x)
DEV void split3(float x, unsigned short& h, unsigned short& m, unsigned short& l) {
    const unsigned u = __float_as_uint(x);
    h = (unsigned short)(u >> 16);
    const float r1 = x - __uint_as_float(u & 0xffff0000u);
    const unsigned u1 = __float_as_uint(r1);
    m = (unsigned short)(u1 >> 16);
    const float r2 = r1 - __uint_as_float(u1 & 0xffff0000u);
    l = (unsigned short)(__float_as_uint(r2) >> 16);
}

DEV void split8store(const float v[8], unsigned short* d) {
    s16x8 vh, vm, vl;
#pragma unroll
    for (int j = 0; j < 8; ++j) {
        unsigned short h, m, l;
        split3(v[j], h, m, l);
        vh[j] = (short)h; vm[j] = (short)m; vl[j] = (short)l;
    }
    *(s16x8*)(d) = vh;
    *(s16x8*)(d + 512) = vm;
    *(s16x8*)(d + 1024) = vl;
}

DEV void mfma6(f32x4& acc, s16x8 ah, s16x8 am, s16x8 al, const unsigned short* bp) {
    const s16x8 bh = *(const s16x8*)(bp);
    const s16x8 bm = *(const s16x8*)(bp + 512);
    const s16x8 bl = *(const s16x8*)(bp + 1024);
    acc = MF(ah, bh, acc);
    acc = MF(ah, bm, acc);
    acc = MF(am, bh, acc);
    acc = MF(ah, bl, acc);
    acc = MF(al, bh, acc);
    acc = MF(am, bm, acc);
}

// ---------------------------------------------------------------- transpose: [N][K] -> [K][N]
__global__ void k_tpose(const float* __restrict__ in, float* __restrict__ out, int N, int K) {
    int total = N * K;
    for (int idx = blockIdx.x * blockDim.x + threadIdx.x; idx < total; idx += gridDim.x * blockDim.x) {
        int n = idx / K, k = idx - n * K;
        out[k * N + n] = in[idx];
    }
}

// ---------------------------------------------------------------- 3-term B-frag pack, strided source
__global__ void k_wpack3(const float* __restrict__ W, unsigned short* __restrict__ WP,
                         int K, int NT, int ldw, int stride, int off) {
    const int idx = blockIdx.x * 256 + threadIdx.x;
    const int total = (K >> 5) * NT * 64;
    if (idx >= total) return;
    const int lane = idx & 63;
    const int nt = (idx >> 6) % NT;
    const int ks = idx / (64 * NT);
    const int col = nt * 16 + (lane & 15);
    const int k0 = ks * 32 + ((lane >> 4) << 3);
    const float* src = W + (size_t)col * ldw + (size_t)k0 * stride + off;
    float v[8];
#pragma unroll
    for (int j = 0; j < 8; ++j) v[j] = src[j * stride];
    split8store(v, WP + (size_t)((ks * NT + nt) * 3) * 512 + lane * 8);
}

// ---------------------------------------------------------------- conv1: [CB,20,8,8] -> a1 [CB,64,256], relu
__global__ __launch_bounds__(256) void k_conv1(const float* __restrict__ in, const float* __restrict__ w,
                                               const float* __restrict__ bias, float* __restrict__ out) {
    __shared__ __align__(16) float img[20 * 100];
    __shared__ __align__(16) float stg[16 * 260];
    const int b = blockIdx.x;
    const int t = threadIdx.x;
    for (int idx = t; idx < 2000; idx += 256) {
        int c = idx / 100, pp = idx - c * 100;
        int y = pp / 10, x = pp - y * 10;
        float v = 0.f;
        if (y >= 1 && y <= 8 && x >= 1 && x <= 8)
            v = in[((size_t)b * 20 + c) * 64 + (y - 1) * 8 + (x - 1)];
        img[idx] = v;
    }
    __syncthreads();
    const int oc = t;
    float acc[64];
    const float bz = bias[oc];
#pragma unroll
    for (int p = 0; p < 64; ++p) acc[p] = bz;
    const float* wrow = w + oc * 180;
    for (int c = 0; c < 20; ++c) {
#pragma unroll
        for (int k = 0; k < 9; ++k) {
            const int ky = k / 3, kx = k - ky * 3;
            const float wv = wrow[c * 9 + k];
            const int base = c * 100 + ky * 10 + kx;
#pragma unroll
            for (int p = 0; p < 64; ++p)
                acc[p] = fmaf(wv, img[base + p + ((p >> 3) << 1)], acc[p]);
        }
    }
#pragma unroll
    for (int cc = 0; cc < 4; ++cc) {
        __syncthreads();
#pragma unroll
        for (int p = 0; p < 16; ++p) stg[p * 260 + t] = acc[cc * 16 + p];
        __syncthreads();
        for (int idx = t; idx < 4096; idx += 256) {
            const int r = idx >> 8, c = idx & 255;
            out[((size_t)b * 64 + cc * 16 + r) * 256 + c] = fmaxf(stg[r * 260 + c], 0.f);
        }
    }
}

// ---------------------------------------------------------------- conv2 MFMA (3-term) + split-plane epilogue
__global__ __launch_bounds__(256) void k_conv2mf(const float* __restrict__ a1,
                                                 const unsigned short* __restrict__ WPC2,
                                                 const float* __restrict__ bias,
                                                 float* __restrict__ xout,
                                                 unsigned short* __restrict__ xh,
                                                 unsigned short* __restrict__ xm,
                                                 unsigned short* __restrict__ xl) {
    __shared__ __align__(16) unsigned short AhS[100 * 132];
    __shared__ __align__(16) unsigned short AmS[100 * 132];
    __shared__ __align__(16) unsigned short AlS[100 * 132];
    const int b = blockIdx.x, t = threadIdx.x;
    const int wv = t >> 6, lane = t & 63;
    f32x4 acc[16];
#pragma unroll
    for (int nt = 0; nt < 16; ++nt) acc[nt] = (f32x4){0.f, 0.f, 0.f, 0.f};
    const int pl = lane & 15;
    const int py = pl >> 3, px = pl & 7;
    const int akoff = (lane >> 4) << 3;
    for (int h = 0; h < 2; ++h) {
        __syncthreads();
        for (int idx = t; idx < 12800; idx += 256) {
            const int pr = idx >> 7, c = idx & 127;
            const int Y = pr / 10, X = pr - Y * 10;
            float v = 0.f;
            if (Y >= 1 && Y <= 8 && X >= 1 && X <= 8)
                v = a1[((size_t)b * 64 + (Y - 1) * 8 + X - 1) * 256 + h * 128 + c];
            unsigned short hh, mm, ll;
            split3(v, hh, mm, ll);
            AhS[pr * 132 + c] = hh;
            AmS[pr * 132 + c] = mm;
            AlS[pr * 132 + c] = ll;
        }
        __syncthreads();
#pragma unroll
        for (int tap = 0; tap < 9; ++tap) {
            const int dy = tap / 3, dx = tap - dy * 3;
            const int prow = (wv * 2 + py + dy) * 10 + px + dx;
            const unsigned short* arh = AhS + prow * 132 + akoff;
            const unsigned short* arm = AmS + prow * 132 + akoff;
            const unsigned short* arl = AlS + prow * 132 + akoff;
#pragma unroll
            for (int ks = 0; ks < 4; ++ks) {
                const s16x8 ah = *(const s16x8*)(arh + ks * 32);
                const s16x8 am = *(const s16x8*)(arm + ks * 32);
                const s16x8 al = *(const s16x8*)(arl + ks * 32);
                const unsigned short* bp = WPC2 + (size_t)(tap * 128 + (h * 4 + ks) * 16) * 1536 + lane * 8;
#pragma unroll
                for (int nt = 0; nt < 16; ++nt) {
                    mfma6(acc[nt], ah, am, al, bp + nt * 1536);
                }
            }
        }
    }
    const int prow0 = wv * 16 + ((lane >> 4) << 2);
    const int ccol = lane & 15;
#pragma unroll
    for (int nt = 0; nt < 16; ++nt) {
        const float bz = bias[nt * 16 + ccol];
#pragma unroll
        for (int i = 0; i < 4; ++i) {
            const float v = fmaxf(acc[nt][i] + bz, 0.f);
            const size_t o = ((size_t)b * 64 + prow0 + i) * 256 + nt * 16 + ccol;
            xout[o] = v;
            unsigned short hh, mm, ll;
            split3(v, hh, mm, ll);
            xh[o] = hh;
            xm[o] = mm;
            xl[o] = ll;
        }
    }
}

// ---------------------------------------------------------------- attention core per (b, head): qkv fp32 in, o splits out
__global__ __launch_bounds__(512) void k_attn2(const float* __restrict__ qkv,
                                               unsigned short* __restrict__ oh, unsigned short* __restrict__ om,
                                               unsigned short* __restrict__ ol) {
    __shared__ __align__(16) float qs[64 * 65];  // q, then reused for P
    __shared__ __align__(16) float ks[64 * 68];  // k, then reused for output staging
    __shared__ __align__(16) float vs[64 * 68];
    __shared__ float pmax[8 * 64];
    __shared__ float psum[8 * 64];
    const int b = blockIdx.x, h = blockIdx.y;
    const int t = threadIdx.x;
    for (int idx = t; idx < 1024; idx += 512) {
        const int rr = idx >> 4, cc = (idx & 15) * 4;
        const float* src = qkv + ((size_t)b * 64 + rr) * 768 + h * 64 + cc;
        const float4 q4 = *(const float4*)(src);
        const float4 k4 = *(const float4*)(src + 256);
        const float4 v4 = *(const float4*)(src + 512);
        qs[rr * 65 + cc + 0] = q4.x; qs[rr * 65 + cc + 1] = q4.y;
        qs[rr * 65 + cc + 2] = q4.z; qs[rr * 65 + cc + 3] = q4.w;
        *(float4*)(ks + rr * 68 + cc) = k4;
        *(float4*)(vs + rr * 68 + cc) = v4;
    }
    __syncthreads();
    const int r = t & 63;
    const int cg = t >> 6;
    float sc[8];
#pragma unroll
    for (int j = 0; j < 8; ++j) sc[j] = 0.f;
    for (int kk = 0; kk < 64; kk += 4) {
        float qv[4];
#pragma unroll
        for (int i = 0; i < 4; ++i) qv[i] = qs[r * 65 + kk + i];
#pragma unroll
        for (int j = 0; j < 8; ++j) {
            const float4 kv = *(const float4*)(ks + (cg * 8 + j) * 68 + kk);
            sc[j] = fmaf(qv[0], kv.x, sc[j]); sc[j] = fmaf(qv[1], kv.y, sc[j]);
            sc[j] = fmaf(qv[2], kv.z, sc[j]); sc[j] = fmaf(qv[3], kv.w, sc[j]);
        }
    }
    float pm = -1e30f;
#pragma unroll
    for (int j = 0; j < 8; ++j) { sc[j] *= 0.125f; pm = fmaxf(pm, sc[j]); }
    pmax[cg * 64 + r] = pm;
    __syncthreads();
    float m = pmax[r];
#pragma unroll
    for (int i = 1; i < 8; ++i) m = fmaxf(m, pmax[i * 64 + r]);
    float pe[8], ps = 0.f;
#pragma unroll
    for (int j = 0; j < 8; ++j) { pe[j] = __expf(sc[j] - m); ps += pe[j]; }
    psum[cg * 64 + r] = ps;
    __syncthreads();
    float den = psum[r];
#pragma unroll
    for (int i = 1; i < 8; ++i) den += psum[i * 64 + r];
    const float rden = 1.f / den;
#pragma unroll
    for (int j = 0; j < 8; ++j) qs[r * 65 + cg * 8 + j] = pe[j] * rden;  // P overwrites q
    __syncthreads();
    float oa[8];
#pragma unroll
    for (int j = 0; j < 8; ++j) oa[j] = 0.f;
    for (int c = 0; c < 64; ++c) {
        const float pv = qs[r * 65 + c];
        const float4 v0 = *(const float4*)(vs + c * 68 + cg * 8);
        const float4 v1 = *(const float4*)(vs + c * 68 + cg * 8 + 4);
        oa[0] = fmaf(pv, v0.x, oa[0]); oa[1] = fmaf(pv, v0.y, oa[1]);
        oa[2] = fmaf(pv, v0.z, oa[2]); oa[3] = fmaf(pv, v0.w, oa[3]);
        oa[4] = fmaf(pv, v1.x, oa[4]); oa[5] = fmaf(pv, v1.y, oa[5]);
        oa[6] = fmaf(pv, v1.z, oa[6]); oa[7] = fmaf(pv, v1.w, oa[7]);
    }
#pragma unroll
    for (int j = 0; j < 8; ++j) ks[r * 68 + cg * 8 + j] = oa[j];
    __syncthreads();
    for (int idx = t; idx < 4096; idx += 512) {
        const int rr = idx >> 6, dd = idx & 63;
        const float v = ks[rr * 68 + dd];
        unsigned short hh, mm, ll;
        split3(v, hh, mm, ll);
        const size_t o = ((size_t)b * 64 + rr) * 256 + h * 64 + dd;
        oh[o] = hh;
        om[o] = mm;
        ol[o] = ll;
    }
}

// ---------------------------------------------------------------- MFMA GEMM 64-row (be1/be2, split-K)
__global__ __launch_bounds__(256) void k_gemm_mf(
    const unsigned short* __restrict__ Ah, const unsigned short* __restrict__ Am,
    const unsigned short* __restrict__ Al,
    const unsigned short* __restrict__ WP, const float* __restrict__ bias,
    float* __restrict__ Cf, unsigned short* __restrict__ Ch, unsigned short* __restrict__ Cm,
    unsigned short* __restrict__ Cl,
    int M, int N, int K, int kChunk, int relu) {
    const int t = threadIdx.x;
    const int wv = t >> 6, lane = t & 63;
    const int row0 = blockIdx.x * 64 + wv * 16;
    const int col0 = blockIdx.y * 64;
    const int NT = N >> 4;
    const int k0 = blockIdx.z * kChunk;
    const int nks = kChunk >> 5;
    f32x4 acc[4];
#pragma unroll
    for (int nt = 0; nt < 4; ++nt) acc[nt] = (f32x4){0.f, 0.f, 0.f, 0.f};
    const int arow = row0 + (lane & 15);
    const size_t aoff = (size_t)arow * K + k0 + ((lane >> 4) << 3);
    const unsigned short* aph = Ah + aoff;
    const unsigned short* apm = Am + aoff;
    const unsigned short* apl = Al + aoff;
    const unsigned short* bp = WP + ((size_t)((k0 >> 5) * NT + (col0 >> 4))) * 1536 + lane * 8;
    const size_t bstride = (size_t)NT * 1536;
    for (int ks = 0; ks < nks; ++ks) {
        const s16x8 ah = *(const s16x8*)aph;
        const s16x8 am = *(const s16x8*)apm;
        const s16x8 al = *(const s16x8*)apl;
        aph += 32; apm += 32; apl += 32;
#pragma unroll
        for (int nt = 0; nt < 4; ++nt) {
            mfma6(acc[nt], ah, am, al, bp + nt * 1536);
        }
        bp += bstride;
    }
    const int crow = row0 + ((lane >> 4) << 2);
    const int ccol = col0 + (lane & 15);
    float bz[4];
#pragma unroll
    for (int nt = 0; nt < 4; ++nt) bz[nt] = bias ? bias[ccol + nt * 16] : 0.f;
    if (Ch) {
#pragma unroll
        for (int nt = 0; nt < 4; ++nt) {
#pragma unroll
            for (int i = 0; i < 4; ++i) {
                float v = acc[nt][i] + bz[nt];
                if (relu) v = fmaxf(v, 0.f);
                unsigned short hh, mm, ll;
                split3(v, hh, mm, ll);
                const size_t o = (size_t)(crow + i) * N + ccol + nt * 16;
                Ch[o] = hh;
                Cm[o] = mm;
                Cl[o] = ll;
            }
        }
    } else {
        float* base = Cf + (size_t)blockIdx.z * M * N;
#pragma unroll
        for (int nt = 0; nt < 4; ++nt) {
#pragma unroll
            for (int i = 0; i < 4; ++i) {
                float v = acc[nt][i] + bz[nt];
                if (relu) v = fmaxf(v, 0.f);
                base[(size_t)(crow + i) * N + ccol + nt * 16] = v;
            }
        }
    }
}

// ---------------------------------------------------------------- MFMA GEMM 128-row: 32 rows/wave, 48 MFMA / 18 loads per ks
__global__ __launch_bounds__(256) void k_gemm_mf128(
    const unsigned short* __restrict__ Ah, const unsigned short* __restrict__ Am,
    const unsigned short* __restrict__ Al,
    const unsigned short* __restrict__ WP, const float* __restrict__ bias,
    float* __restrict__ Cf, unsigned short* __restrict__ Ch, unsigned short* __restrict__ Cm,
    unsigned short* __restrict__ Cl,
    int M, int N, int K, int relu) {
    const int t = threadIdx.x;
    const int wv = t >> 6, lane = t & 63;
    const int row0 = blockIdx.x * 128 + wv * 32;
    const int col0 = blockIdx.y * 64;
    const int NT = N >> 4;
    const int nks = K >> 5;
    f32x4 acc0[4], acc1[4];
#pragma unroll
    for (int nt = 0; nt < 4; ++nt) {
        acc0[nt] = (f32x4){0.f, 0.f, 0.f, 0.f};
        acc1[nt] = (f32x4){0.f, 0.f, 0.f, 0.f};
    }
    const size_t aoff0 = (size_t)(row0 + (lane & 15)) * K + ((lane >> 4) << 3);
    const size_t aoff1 = aoff0 + (size_t)16 * K;
    const unsigned short* bp = WP + (size_t)(col0 >> 4) * 1536 + lane * 8;
    const size_t bstride = (size_t)NT * 1536;
    for (int ks = 0; ks < nks; ++ks) {
        const size_t ao = ks * 32;
        const s16x8 a0h = *(const s16x8*)(Ah + aoff0 + ao);
        const s16x8 a0m = *(const s16x8*)(Am + aoff0 + ao);
        const s16x8 a0l = *(const s16x8*)(Al + aoff0 + ao);
        const s16x8 a1h = *(const s16x8*)(Ah + aoff1 + ao);
        const s16x8 a1m = *(const s16x8*)(Am + aoff1 + ao);
        const s16x8 a1l = *(const s16x8*)(Al + aoff1 + ao);
#pragma unroll
        for (int nt = 0; nt < 4; ++nt) {
            const unsigned short* bb = bp + nt * 1536;
            const s16x8 bh = *(const s16x8*)(bb);
            const s16x8 bm = *(const s16x8*)(bb + 512);
            const s16x8 bl = *(const s16x8*)(bb + 1024);
            acc0[nt] = MF(a0h, bh, acc0[nt]);
            acc0[nt] = MF(a0h, bm, acc0[nt]);
            acc0[nt] = MF(a0m, bh, acc0[nt]);
            acc0[nt] = MF(a0h, bl, acc0[nt]);
            acc0[nt] = MF(a0l, bh, acc0[nt]);
            acc0[nt] = MF(a0m, bm, acc0[nt]);
            acc1[nt] = MF(a1h, bh, acc1[nt]);
            acc1[nt] = MF(a1h, bm, acc1[nt]);
            acc1[nt] = MF(a1m, bh, acc1[nt]);
            acc1[nt] = MF(a1h, bl, acc1[nt]);
            acc1[nt] = MF(a1l, bh, acc1[nt]);
            acc1[nt] = MF(a1m, bm, acc1[nt]);
        }
        bp += bstride;
    }
    const int crow0 = row0 + ((lane >> 4) << 2);
    const int ccol = col0 + (lane & 15);
    float bz[4];
#pragma unroll
    for (int nt = 0; nt < 4; ++nt) bz[nt] = bias ? bias[ccol + nt * 16] : 0.f;
#pragma unroll
    for (int half = 0; half < 2; ++half) {
        const int crow = crow0 + half * 16;
        f32x4* ac = half ? acc1 : acc0;
        if (Ch) {
#pragma unroll
            for (int nt = 0; nt < 4; ++nt) {
#pragma unroll
                for (int i = 0; i < 4; ++i) {
                    float v = ac[nt][i] + bz[nt];
                    if (relu) v = fmaxf(v, 0.f);
                    unsigned short hh, mm, ll;
                    split3(v, hh, mm, ll);
                    const size_t o = (size_t)(crow + i) * N + ccol + nt * 16;
                    Ch[o] = hh;
                    Cm[o] = mm;
                    Cl[o] = ll;
                }
            }
        } else {
#pragma unroll
            for (int nt = 0; nt < 4; ++nt) {
#pragma unroll
                for (int i = 0; i < 4; ++i) {
                    float v = ac[nt][i] + bz[nt];
                    if (relu) v = fmaxf(v, 0.f);
                    Cf[(size_t)(crow + i) * N + ccol + nt * 16] = v;
                }
            }
        }
    }
}

// ---------------------------------------------------------------- x = LN(x + add); writes fp32 + 3-plane split
__global__ __launch_bounds__(256) void k_ln_add(float* __restrict__ x, const float* __restrict__ add,
                                                const float* __restrict__ g, const float* __restrict__ bta,
                                                unsigned short* __restrict__ sh, unsigned short* __restrict__ sm,
                                                unsigned short* __restrict__ sl) {
    const int t = threadIdx.x;
    const size_t r = (size_t)blockIdx.x * 4 + (t >> 6);
    const int lane = t & 63;
    float4 xv = *(const float4*)(x + r * 256 + lane * 4);
    const float4 av = *(const float4*)(add + r * 256 + lane * 4);
    const float4 v = make_float4(xv.x + av.x, xv.y + av.y, xv.z + av.z, xv.w + av.w);
    float s = v.x + v.y + v.z + v.w;
    float ss = fmaf(v.x, v.x, fmaf(v.y, v.y, fmaf(v.z, v.z, v.w * v.w)));
#pragma unroll
    for (int m = 32; m; m >>= 1) { s += __shfl_xor(s, m); ss += __shfl_xor(ss, m); }
    const float mean = s * (1.f / 256.f);
    const float var = ss * (1.f / 256.f) - mean * mean;
    const float rstd = rsqrtf(var + 1e-5f);
    const float4 g4 = *(const float4*)(g + lane * 4);
    const float4 b4 = *(const float4*)(bta + lane * 4);
    float4 ov;
    ov.x = (v.x - mean) * rstd * g4.x + b4.x;
    ov.y = (v.y - mean) * rstd * g4.y + b4.y;
    ov.z = (v.z - mean) * rstd * g4.z + b4.z;
    ov.w = (v.w - mean) * rstd * g4.w + b4.w;
    *(float4*)(x + r * 256 + lane * 4) = ov;
    const float vv[4] = {ov.x, ov.y, ov.z, ov.w};
    unsigned short hh[4], mm[4], ll[4];
#pragma unroll
    for (int j = 0; j < 4; ++j) split3(vv[j], hh[j], mm[j], ll[j]);
    *(ushort4*)(sh + r * 256 + lane * 4) = make_ushort4(hh[0], hh[1], hh[2], hh[3]);
    *(ushort4*)(sm + r * 256 + lane * 4) = make_ushort4(mm[0], mm[1], mm[2], mm[3]);
    *(ushort4*)(sl + r * 256 + lane * 4) = make_ushort4(ll[0], ll[1], ll[2], ll[3]);
}

// ---------------------------------------------------------------- be1 split-K reduce + bias + relu -> 3-plane split
__global__ void k_be1_reduce(const float* __restrict__ parts, const float* __restrict__ bias,
                             unsigned short* __restrict__ oh, unsigned short* __restrict__ om,
                             unsigned short* __restrict__ ol, int n) {
    const int idx = blockIdx.x * blockDim.x + threadIdx.x;
    if (idx < n) {
        float s = bias[idx & 255];
#pragma unroll
        for (int p = 0; p < 8; ++p) s += parts[(size_t)p * n + idx];
        s = fmaxf(s, 0.f);
        unsigned short hh, mm, ll;
        split3(s, hh, mm, ll);
        oh[idx] = hh;
        om[idx] = mm;
        ol[idx] = ll;
    }
}

// ================================================================ HRM recurrence, MFMA — frag LDS, 16 waves (1 N-tile/wave)
DEV void splitpass(const float* scr, unsigned short* frag, int t) {
    const int ks = t >> 6, ln = t & 63;
    const int row = ln & 15;
    const int k0 = ks * 32 + ((ln >> 4) << 3);
    const float* s = scr + row * 260 + k0;
    const float4 p = *(const float4*)s;
    const float4 q = *(const float4*)(s + 4);
    const float v[8] = {p.x, p.y, p.z, p.w, q.x, q.y, q.z, q.w};
    split8store(v, frag + (ks * 3) * 512 + ln * 8);
}

DEV void rungemm1(f32x4& a0, const unsigned short* __restrict__ WP, int KS,
                  const unsigned short* f0, const unsigned short* f1, const unsigned short* f2,
                  int wv, int lane) {
    for (int ks = 0; ks < KS; ++ks) {
        const unsigned short* fa = (ks < 8) ? f0 : ((ks < 16) ? f1 : f2);
        const int kl = ks & 7;
        const unsigned short* ap = fa + (kl * 3) * 512 + lane * 8;
        const s16x8 ah = *(const s16x8*)(ap);
        const s16x8 am = *(const s16x8*)(ap + 512);
        const s16x8 al = *(const s16x8*)(ap + 1024);
        const unsigned short* bp = WP + (size_t)((ks * 16 + wv) * 3) * 512 + lane * 8;
        mfma6(a0, ah, am, al, bp);
    }
}

DEV void storeC1(f32x4 a0, const float* __restrict__ bias, float* scr, int wv, int lane) {
    const int rb = (lane >> 4) * 4;
    const int c0 = wv * 16 + (lane & 15);
    const float bz = bias[c0];
    scr[(rb + 0) * 260 + c0] = fmaxf(a0[0] + bz, 0.f);
    scr[(rb + 1) * 260 + c0] = fmaxf(a0[1] + bz, 0.f);
    scr[(rb + 2) * 260 + c0] = fmaxf(a0[2] + bz, 0.f);
    scr[(rb + 3) * 260 + c0] = fmaxf(a0[3] + bz, 0.f);
}

DEV void lnpass(float* scr, const float* __restrict__ g, const float* __restrict__ bb, int t) {
    const int row = 2 * (t >> 6) + ((t & 63) >> 5);
    const int c0 = (t & 31) * 8;
    float* s = scr + row * 260 + c0;
    const float4 x0 = *(const float4*)s;
    const float4 x1 = *(const float4*)(s + 4);
    float sum = x0.x + x0.y + x0.z + x0.w + x1.x + x1.y + x1.z + x1.w;
    float sq = fmaf(x0.x, x0.x, fmaf(x0.y, x0.y, fmaf(x0.z, x0.z, x0.w * x0.w)));
    sq = fmaf(x1.x, x1.x, fmaf(x1.y, x1.y, fmaf(x1.z, x1.z, fmaf(x1.w, x1.w, sq))));
#pragma unroll
    for (int m = 16; m; m >>= 1) { sum += __shfl_xor(sum, m); sq += __shfl_xor(sq, m); }
    const float mean = sum * (1.f / 256.f);
    const float var = sq * (1.f / 256.f) - mean * mean;
    const float rstd = rsqrtf(var + 1e-5f);
    const float4 g0 = *(const float4*)(g + c0);
    const float4 g1 = *(const float4*)(g + c0 + 4);
    const float4 b0 = *(const float4*)(bb + c0);
    const float4 b1 = *(const float4*)(bb + c0 + 4);
    float4 o0, o1;
    o0.x = (x0.x - mean) * rstd * g0.x + b0.x;
    o0.y = (x0.y - mean) * rstd * g0.y + b0.y;
    o0.z = (x0.z - mean) * rstd * g0.z + b0.z;
    o0.w = (x0.w - mean) * rstd * g0.w + b0.w;
    o1.x = (x1.x - mean) * rstd * g1.x + b1.x;
    o1.y = (x1.y - mean) * rstd * g1.y + b1.y;
    o1.z = (x1.z - mean) * rstd * g1.z + b1.z;
    o1.w = (x1.w - mean) * rstd * g1.w + b1.w;
    *(float4*)s = o0;
    *(float4*)(s + 4) = o1;
}

__global__ __launch_bounds__(1024, 4) void k_hrm(const float* __restrict__ be,
        const unsigned short* __restrict__ L1P, const float* __restrict__ L1b,
        const unsigned short* __restrict__ L2P, const float* __restrict__ L2b,
        const float* __restrict__ Lg, const float* __restrict__ Lbt,
        const unsigned short* __restrict__ H1P, const float* __restrict__ H1b,
        const unsigned short* __restrict__ H2P, const float* __restrict__ H2b,
        const float* __restrict__ Hg, const float* __restrict__ Hbt,
        const unsigned short* __restrict__ v1P, const float* __restrict__ v1b,
        const float* __restrict__ v2T, const float* __restrict__ v2b,
        float* __restrict__ out) {
    __shared__ __align__(16) unsigned short fzL[12288];
    __shared__ __align__(16) unsigned short fzH[12288];
    __shared__ __align__(16) unsigned short fbe[12288];
    __shared__ __align__(16) unsigned short fh1[12288];
    __shared__ __align__(16) float scr[16 * 260];
    const int t = threadIdx.x;
    const int b0 = blockIdx.x * 16;
    const int wv = t >> 6, lane = t & 63;
    for (int i = t; i < 12288; i += 1024) { fzL[i] = 0; fzH[i] = 0; }
    if (t < 512) {
        const int ks = t >> 6, ln = t & 63;
        const int row = ln & 15;
        const int k0 = ks * 32 + ((ln >> 4) << 3);
        const float* s = be + (size_t)(b0 + row) * 256 + k0;
        const float4 p = *(const float4*)s;
        const float4 q = *(const float4*)(s + 4);
        const float v[8] = {p.x, p.y, p.z, p.w, q.x, q.y, q.z, q.w};
        split8store(v, fbe + (ks * 3) * 512 + ln * 8);
    }
    __syncthreads();
    const f32x4 zero4 = {0.f, 0.f, 0.f, 0.f};
    for (int it = 0; it < 64; ++it) {
        // h1 = relu(cat(zL,zH,be) @ L1^T + b)
        f32x4 a0 = zero4;
        rungemm1(a0, L1P, 24, fzL, fzH, fbe, wv, lane);
        storeC1(a0, L1b, scr, wv, lane);
        __syncthreads();
        if (t < 512) splitpass(scr, fh1, t);
        __syncthreads();
        // zL = LN(relu(h1 @ L2^T + b))
        a0 = zero4;
        rungemm1(a0, L2P, 8, fh1, fh1, fh1, wv, lane);
        storeC1(a0, L2b, scr, wv, lane);
        __syncthreads();
        if (t < 512) lnpass(scr, Lg, Lbt, t);
        __syncthreads();
        if (t < 512) splitpass(scr, fzL, t);
        __syncthreads();
        if (((it + 1) & 7) == 0) {
            a0 = zero4;
            rungemm1(a0, H1P, 16, fzH, fzL, fzL, wv, lane);
            storeC1(a0, H1b, scr, wv, lane);
            __syncthreads();
            if (t < 512) splitpass(scr, fh1, t);
            __syncthreads();
            a0 = zero4;
            rungemm1(a0, H2P, 8, fh1, fh1, fh1, wv, lane);
            storeC1(a0, H2b, scr, wv, lane);
            __syncthreads();
            if (t < 512) lnpass(scr, Hg, Hbt, t);
            __syncthreads();
            if (t < 512) splitpass(scr, fzH, t);
            __syncthreads();
        }
    }
    // head: out = relu(zH @ v1^T + b) @ v2^T + b
    f32x4 a0 = zero4;
    rungemm1(a0, v1P, 8, fzH, fzH, fzH, wv, lane);
    storeC1(a0, v1b, scr, wv, lane);
    __syncthreads();
    for (int idx = t; idx < 2048; idx += 1024) {
        const int r = idx >> 7, oo = idx & 127;
        float s = v2b[oo];
        for (int kk = 0; kk < 256; kk += 4) {
            const float4 c4 = *(const float4*)(&scr[r * 260 + kk]);
            s = fmaf(c4.x, v2T[(kk + 0) * 128 + oo], s);
            s = fmaf(c4.y, v2T[(kk + 1) * 128 + oo], s);
            s = fmaf(c4.z, v2T[(kk + 2) * 128 + oo], s);
            s = fmaf(c4.w, v2T[(kk + 3) * 128 + oo], s);
        }
        out[(size_t)(b0 + r) * 128 + oo] = s;
    }
}

// ================================================================ launch
extern "C" void kernel_launch(void* const* d_in, const int* in_sizes, int n_in,
                              void* d_out, int out_size, void* d_ws, size_t ws_size,
                              hipStream_t stream) {
    const float* bitplanes  = (const float*)d_in[0];
    const float* conv1_w    = (const float*)d_in[1];
    const float* conv1_b    = (const float*)d_in[2];
    const float* conv2_w    = (const float*)d_in[3];
    const float* conv2_b    = (const float*)d_in[4];
    const float* in_proj_w  = (const float*)d_in[5];
    const float* in_proj_b  = (const float*)d_in[6];
    const float* out_proj_w = (const float*)d_in[7];
    const float* out_proj_b = (const float*)d_in[8];
    const float* ln1_g      = (const float*)d_in[9];
    const float* ln1_b      = (const float*)d_in[10];
    const float* ff1_w      = (const float*)d_in[11];
    const float* ff1_b      = (const float*)d_in[12];
    const float* ff2_w      = (const float*)d_in[13];
    const float* ff2_b      = (const float*)d_in[14];
    const float* ln2_g      = (const float*)d_in[15];
    const float* ln2_b      = (const float*)d_in[16];
    const float* be1_w      = (const float*)d_in[17];
    const float* be1_b      = (const float*)d_in[18];
    const float* be2_w      = (const float*)d_in[19];
    const float* be2_b      = (const float*)d_in[20];
    const float* L1_w       = (const float*)d_in[21];
    const float* L1_b       = (const float*)d_in[22];
    const float* L2_w       = (const float*)d_in[23];
    const float* L2_b       = (const float*)d_in[24];
    const float* Lln_g      = (const float*)d_in[25];
    const float* Lln_b      = (const float*)d_in[26];
    const float* H1_w       = (const float*)d_in[27];
    const float* H1_b       = (const float*)d_in[28];
    const float* H2_w       = (const float*)d_in[29];
    const float* H2_b       = (const float*)d_in[30];
    const float* Hln_g      = (const float*)d_in[31];
    const float* Hln_b      = (const float*)d_in[32];
    const float* v1_w       = (const float*)d_in[33];
    const float* v1_b       = (const float*)d_in[34];
    const float* v2_w       = (const float*)d_in[35];
    const float* v2_b       = (const float*)d_in[36];

    // per-chunk floats = CB*106880; persistent tail = 9,404,416 floats
    const size_t persist = 9404416ull;
    int CB = 64;
    for (int c = 2048; c >= 64; c >>= 1) {
        size_t needBytes = ((size_t)c * 106880ull + persist) * 4ull;
        if (needBytes <= ws_size) { CB = c; break; }
    }
    const int NCH = 2048 / CB;

    float* ws = (float*)d_ws;
    float* a1buf = ws;                                  // CB*16384 fp32
    float* xbuf  = a1buf + (size_t)CB * 16384;          // CB*16384 fp32
    float* sbuf  = xbuf + (size_t)CB * 16384;           // CB*24576 fl = 3 bf16 planes CB*64*256
    float* tbuf  = sbuf + (size_t)CB * 24576;           // CB*49152 fl (qkv fp32 / ff1 planes / be1 parts)
    float* bemf  = tbuf + (size_t)CB * 49152;           // CB*384 fl = 3 bf16 planes CB*256
    float* wpQf  = bemf + (size_t)CB * 384;             // 294,912 (in_proj 3-term pack)
    float* v2T   = wpQf + 294912;                       // 32,768
    float* L1Pf  = v2T + 32768;                         // 294,912
    float* L2Pf  = L1Pf + 294912;                       // 98,304
    float* H1Pf  = L2Pf + 98304;                        // 196,608
    float* H2Pf  = H1Pf + 196608;                       // 98,304
    float* v1Pf  = H2Pf + 98304;                        // 98,304
    float* beB   = v1Pf + 98304;                        // 524,288
    float* wpOf  = beB + 524288;                        // 98,304
    float* wpF1f = wpOf + 98304;                        // 196,608
    float* wpF2f = wpF1f + 196608;                      // 196,608
    float* wpB1f = wpF2f + 196608;                      // 6,291,456
    float* wpB2f = wpB1f + 6291456;                     // 98,304
    float* wpC2f = wpB2f + 98304;                       // 884,736

    unsigned short* soh = (unsigned short*)sbuf;
    unsigned short* som = soh + (size_t)CB * 16384;
    unsigned short* sol = som + (size_t)CB * 16384;
    unsigned short* tbh = (unsigned short*)tbuf;
    unsigned short* tbm = tbh + (size_t)CB * 32768;
    unsigned short* tbl = tbm + (size_t)CB * 32768;
    unsigned short* bemh = (unsigned short*)bemf;
    unsigned short* bemm = bemh + (size_t)CB * 256;
    unsigned short* beml = bemm + (size_t)CB * 256;
    unsigned short* wpQ = (unsigned short*)wpQf;
    unsigned short* L1P = (unsigned short*)L1Pf;
    unsigned short* L2P = (unsigned short*)L2Pf;
    unsigned short* H1P = (unsigned short*)H1Pf;
    unsigned short* H2P = (unsigned short*)H2Pf;
    unsigned short* v1P = (unsigned short*)v1Pf;
    unsigned short* wpO = (unsigned short*)wpOf;
    unsigned short* wpF1 = (unsigned short*)wpF1f;
    unsigned short* wpF2 = (unsigned short*)wpF2f;
    unsigned short* wpB1 = (unsigned short*)wpB1f;
    unsigned short* wpB2 = (unsigned short*)wpB2f;
    unsigned short* wpC2 = (unsigned short*)wpC2f;

    // weight prep (once) — all packs 3-term
    k_tpose<<<64, 256, 0, stream>>>(v2_w, v2T, 128, 256);
    k_wpack3<<<96, 256, 0, stream>>>(in_proj_w, wpQ, 256, 48, 256, 1, 0);
    k_wpack3<<<96, 256, 0, stream>>>(L1_w, L1P, 768, 16, 768, 1, 0);
    k_wpack3<<<32, 256, 0, stream>>>(L2_w, L2P, 256, 16, 256, 1, 0);
    k_wpack3<<<64, 256, 0, stream>>>(H1_w, H1P, 512, 16, 512, 1, 0);
    k_wpack3<<<32, 256, 0, stream>>>(H2_w, H2P, 256, 16, 256, 1, 0);
    k_wpack3<<<32, 256, 0, stream>>>(v1_w, v1P, 256, 16, 256, 1, 0);
    k_wpack3<<<32, 256, 0, stream>>>(out_proj_w, wpO, 256, 16, 256, 1, 0);
    k_wpack3<<<64, 256, 0, stream>>>(ff1_w, wpF1, 256, 32, 256, 1, 0);
    k_wpack3<<<64, 256, 0, stream>>>(ff2_w, wpF2, 512, 16, 512, 1, 0);
    k_wpack3<<<2048, 256, 0, stream>>>(be1_w, wpB1, 16384, 16, 16384, 1, 0);
    k_wpack3<<<32, 256, 0, stream>>>(be2_w, wpB2, 256, 16, 256, 1, 0);
    for (int tap = 0; tap < 9; ++tap)
        k_wpack3<<<32, 256, 0, stream>>>(conv2_w, wpC2 + (size_t)tap * 196608, 256, 16, 2304, 9, tap);

    for (int ch = 0; ch < NCH; ++ch) {
        const float* bp_c = bitplanes + (size_t)ch * CB * 20 * 64;
        // conv encoder (conv2 emits x fp32 + split planes)
        k_conv1<<<CB, 256, 0, stream>>>(bp_c, conv1_w, conv1_b, a1buf);
        k_conv2mf<<<CB, 256, 0, stream>>>(a1buf, wpC2, conv2_b, xbuf, soh, som, sol);
        // qkv projection (wide MFMA GEMM) then attention core
        k_gemm_mf128<<<dim3(CB / 2, 12), 256, 0, stream>>>(soh, som, sol, wpQ, in_proj_b,
                                                           tbuf, nullptr, nullptr, nullptr,
                                                           CB * 64, 768, 256, 0);
        k_attn2<<<dim3(CB, 4), 512, 0, stream>>>(tbuf, soh, som, sol);
        k_gemm_mf128<<<dim3(CB / 2, 4), 256, 0, stream>>>(soh, som, sol, wpO, out_proj_b,
                                                          a1buf, nullptr, nullptr, nullptr,
                                                          CB * 64, 256, 256, 0);
        k_ln_add<<<CB * 16, 256, 0, stream>>>(xbuf, a1buf, ln1_g, ln1_b, soh, som, sol);
        k_gemm_mf128<<<dim3(CB / 2, 8), 256, 0, stream>>>(soh, som, sol, wpF1, ff1_b,
                                                          nullptr, tbh, tbm, tbl,
                                                          CB * 64, 512, 256, 1);
        k_gemm_mf128<<<dim3(CB / 2, 4), 256, 0, stream>>>(tbh, tbm, tbl, wpF2, ff2_b,
                                                          a1buf, nullptr, nullptr, nullptr,
                                                          CB * 64, 256, 512, 0);
        k_ln_add<<<CB * 16, 256, 0, stream>>>(xbuf, a1buf, ln2_g, ln2_b, soh, som, sol);
        // board embedding: be = relu(relu(xf@be1^T+b)@be2^T+b)
        k_gemm_mf<<<dim3(CB / 64, 4, 8), 256, 0, stream>>>(soh, som, sol, wpB1, nullptr,
                                                           tbuf, nullptr, nullptr, nullptr,
                                                           CB, 256, 16384, 2048, 0);
        k_be1_reduce<<<CB, 256, 0, stream>>>(tbuf, be1_b, bemh, bemm, beml, CB * 256);
        k_gemm_mf<<<dim3(CB / 64, 4, 1), 256, 0, stream>>>(bemh, bemm, beml, wpB2, be2_b,
                                                           beB + (size_t)ch * CB * 256, nullptr, nullptr, nullptr,
                                                           CB, 256, 256, 256, 1);
    }

    // HRM recurrence + head (MFMA, 128 blocks x 16 rows, 16 waves)
    k_hrm<<<128, 1024, 0, stream>>>(beB, L1P, L1_b, L2P, L2_b, Lln_g, Lln_b,
                                    H1P, H1_b, H2P, H2_b, Hln_g, Hln_b,
                                    v1P, v1_b, v2T, v2_b, (float*)d_out);
}

// Round 14
// 4983.862 us; speedup vs baseline: 1.0617x; 1.0329x over previous
//
#include <hip/hip_runtime.h>
#include <hip/hip_bf16.h>
#include <math.h>

#define DEV __device__ __forceinline__

typedef __attribute__((ext_vector_type(8))) short s16x8;
typedef __attribute__((ext_vector_type(4))) float f32x4;

DEV f32x4 MF(s16x8 a, s16x8 b, f32x4 c) {
    return __builtin_amdgcn_mfma_f32_16x16x32_bf16(a, b, c, 0, 0, 0);
}

// 3-term bf16 split (exact truncation residuals): x = h + m + l + O(2^-24 x)
DEV void split3(float x, unsigned short& h, unsigned short& m, unsigned short& l) {
    const unsigned u = __float_as_uint(x);
    h = (unsigned short)(u >> 16);
    const float r1 = x - __uint_as_float(u & 0xffff0000u);
    const unsigned u1 = __float_as_uint(r1);
    m = (unsigned short)(u1 >> 16);
    const float r2 = r1 - __uint_as_float(u1 & 0xffff0000u);
    l = (unsigned short)(__float_as_uint(r2) >> 16);
}

DEV void split8store(const float v[8], unsigned short* d) {
    s16x8 vh, vm, vl;
#pragma unroll
    for (int j = 0; j < 8; ++j) {
        unsigned short h, m, l;
        split3(v[j], h, m, l);
        vh[j] = (short)h; vm[j] = (short)m; vl[j] = (short)l;
    }
    *(s16x8*)(d) = vh;
    *(s16x8*)(d + 512) = vm;
    *(s16x8*)(d + 1024) = vl;
}

DEV void mfma6(f32x4& acc, s16x8 ah, s16x8 am, s16x8 al, const unsigned short* bp) {
    const s16x8 bh = *(const s16x8*)(bp);
    const s16x8 bm = *(const s16x8*)(bp + 512);
    const s16x8 bl = *(const s16x8*)(bp + 1024);
    acc = MF(ah, bh, acc);
    acc = MF(ah, bm, acc);
    acc = MF(am, bh, acc);
    acc = MF(ah, bl, acc);
    acc = MF(al, bh, acc);
    acc = MF(am, bm, acc);
}

// ---------------------------------------------------------------- transpose: [N][K] -> [K][N]
__global__ void k_tpose(const float* __restrict__ in, float* __restrict__ out, int N, int K) {
    int total = N * K;
    for (int idx = blockIdx.x * blockDim.x + threadIdx.x; idx < total; idx += gridDim.x * blockDim.x) {
        int n = idx / K, k = idx - n * K;
        out[k * N + n] = in[idx];
    }
}

// ---------------------------------------------------------------- 3-term B-frag pack, strided source
__global__ void k_wpack3(const float* __restrict__ W, unsigned short* __restrict__ WP,
                         int K, int NT, int ldw, int stride, int off) {
    const int idx = blockIdx.x * 256 + threadIdx.x;
    const int total = (K >> 5) * NT * 64;
    if (idx >= total) return;
    const int lane = idx & 63;
    const int nt = (idx >> 6) % NT;
    const int ks = idx / (64 * NT);
    const int col = nt * 16 + (lane & 15);
    const int k0 = ks * 32 + ((lane >> 4) << 3);
    const float* src = W + (size_t)col * ldw + (size_t)k0 * stride + off;
    float v[8];
#pragma unroll
    for (int j = 0; j < 8; ++j) v[j] = src[j * stride];
    split8store(v, WP + (size_t)((ks * NT + nt) * 3) * 512 + lane * 8);
}

// ---------------------------------------------------------------- conv1: [CB,20,8,8] -> a1 [CB,64,256], relu
__global__ __launch_bounds__(256) void k_conv1(const float* __restrict__ in, const float* __restrict__ w,
                                               const float* __restrict__ bias, float* __restrict__ out) {
    __shared__ __align__(16) float img[20 * 100];
    __shared__ __align__(16) float stg[16 * 260];
    const int b = blockIdx.x;
    const int t = threadIdx.x;
    for (int idx = t; idx < 2000; idx += 256) {
        int c = idx / 100, pp = idx - c * 100;
        int y = pp / 10, x = pp - y * 10;
        float v = 0.f;
        if (y >= 1 && y <= 8 && x >= 1 && x <= 8)
            v = in[((size_t)b * 20 + c) * 64 + (y - 1) * 8 + (x - 1)];
        img[idx] = v;
    }
    __syncthreads();
    const int oc = t;
    float acc[64];
    const float bz = bias[oc];
#pragma unroll
    for (int p = 0; p < 64; ++p) acc[p] = bz;
    const float* wrow = w + oc * 180;
    for (int c = 0; c < 20; ++c) {
#pragma unroll
        for (int k = 0; k < 9; ++k) {
            const int ky = k / 3, kx = k - ky * 3;
            const float wv = wrow[c * 9 + k];
            const int base = c * 100 + ky * 10 + kx;
#pragma unroll
            for (int p = 0; p < 64; ++p)
                acc[p] = fmaf(wv, img[base + p + ((p >> 3) << 1)], acc[p]);
        }
    }
#pragma unroll
    for (int cc = 0; cc < 4; ++cc) {
        __syncthreads();
#pragma unroll
        for (int p = 0; p < 16; ++p) stg[p * 260 + t] = acc[cc * 16 + p];
        __syncthreads();
        for (int idx = t; idx < 4096; idx += 256) {
            const int r = idx >> 8, c = idx & 255;
            out[((size_t)b * 64 + cc * 16 + r) * 256 + c] = fmaxf(stg[r * 260 + c], 0.f);
        }
    }
}

// ---------------------------------------------------------------- conv2 MFMA (3-term) + split-plane epilogue
__global__ __launch_bounds__(256) void k_conv2mf(const float* __restrict__ a1,
                                                 const unsigned short* __restrict__ WPC2,
                                                 const float* __restrict__ bias,
                                                 float* __restrict__ xout,
                                                 unsigned short* __restrict__ xh,
                                                 unsigned short* __restrict__ xm,
                                                 unsigned short* __restrict__ xl) {
    __shared__ __align__(16) unsigned short AhS[100 * 132];
    __shared__ __align__(16) unsigned short AmS[100 * 132];
    __shared__ __align__(16) unsigned short AlS[100 * 132];
    const int b = blockIdx.x, t = threadIdx.x;
    const int wv = t >> 6, lane = t & 63;
    f32x4 acc[16];
#pragma unroll
    for (int nt = 0; nt < 16; ++nt) acc[nt] = (f32x4){0.f, 0.f, 0.f, 0.f};
    const int pl = lane & 15;
    const int py = pl >> 3, px = pl & 7;
    const int akoff = (lane >> 4) << 3;
    for (int h = 0; h < 2; ++h) {
        __syncthreads();
        for (int idx = t; idx < 12800; idx += 256) {
            const int pr = idx >> 7, c = idx & 127;
            const int Y = pr / 10, X = pr - Y * 10;
            float v = 0.f;
            if (Y >= 1 && Y <= 8 && X >= 1 && X <= 8)
                v = a1[((size_t)b * 64 + (Y - 1) * 8 + X - 1) * 256 + h * 128 + c];
            unsigned short hh, mm, ll;
            split3(v, hh, mm, ll);
            AhS[pr * 132 + c] = hh;
            AmS[pr * 132 + c] = mm;
            AlS[pr * 132 + c] = ll;
        }
        __syncthreads();
#pragma unroll
        for (int tap = 0; tap < 9; ++tap) {
            const int dy = tap / 3, dx = tap - dy * 3;
            const int prow = (wv * 2 + py + dy) * 10 + px + dx;
            const unsigned short* arh = AhS + prow * 132 + akoff;
            const unsigned short* arm = AmS + prow * 132 + akoff;
            const unsigned short* arl = AlS + prow * 132 + akoff;
#pragma unroll
            for (int ks = 0; ks < 4; ++ks) {
                const s16x8 ah = *(const s16x8*)(arh + ks * 32);
                const s16x8 am = *(const s16x8*)(arm + ks * 32);
                const s16x8 al = *(const s16x8*)(arl + ks * 32);
                const unsigned short* bp = WPC2 + (size_t)(tap * 128 + (h * 4 + ks) * 16) * 1536 + lane * 8;
#pragma unroll
                for (int nt = 0; nt < 16; ++nt) {
                    mfma6(acc[nt], ah, am, al, bp + nt * 1536);
                }
            }
        }
    }
    const int prow0 = wv * 16 + ((lane >> 4) << 2);
    const int ccol = lane & 15;
#pragma unroll
    for (int nt = 0; nt < 16; ++nt) {
        const float bz = bias[nt * 16 + ccol];
#pragma unroll
        for (int i = 0; i < 4; ++i) {
            const float v = fmaxf(acc[nt][i] + bz, 0.f);
            const size_t o = ((size_t)b * 64 + prow0 + i) * 256 + nt * 16 + ccol;
            xout[o] = v;
            unsigned short hh, mm, ll;
            split3(v, hh, mm, ll);
            xh[o] = hh;
            xm[o] = mm;
            xl[o] = ll;
        }
    }
}

// ---------------------------------------------------------------- attention core per (b, head): qkv fp32 in, o splits out
__global__ __launch_bounds__(512) void k_attn2(const float* __restrict__ qkv,
                                               unsigned short* __restrict__ oh, unsigned short* __restrict__ om,
                                               unsigned short* __restrict__ ol) {
    __shared__ __align__(16) float qs[64 * 65];  // q, then reused for P
    __shared__ __align__(16) float ks[64 * 68];  // k, then reused for output staging
    __shared__ __align__(16) float vs[64 * 68];
    __shared__ float pmax[8 * 64];
    __shared__ float psum[8 * 64];
    const int b = blockIdx.x, h = blockIdx.y;
    const int t = threadIdx.x;
    for (int idx = t; idx < 1024; idx += 512) {
        const int rr = idx >> 4, cc = (idx & 15) * 4;
        const float* src = qkv + ((size_t)b * 64 + rr) * 768 + h * 64 + cc;
        const float4 q4 = *(const float4*)(src);
        const float4 k4 = *(const float4*)(src + 256);
        const float4 v4 = *(const float4*)(src + 512);
        qs[rr * 65 + cc + 0] = q4.x; qs[rr * 65 + cc + 1] = q4.y;
        qs[rr * 65 + cc + 2] = q4.z; qs[rr * 65 + cc + 3] = q4.w;
        *(float4*)(ks + rr * 68 + cc) = k4;
        *(float4*)(vs + rr * 68 + cc) = v4;
    }
    __syncthreads();
    const int r = t & 63;
    const int cg = t >> 6;
    float sc[8];
#pragma unroll
    for (int j = 0; j < 8; ++j) sc[j] = 0.f;
    for (int kk = 0; kk < 64; kk += 4) {
        float qv[4];
#pragma unroll
        for (int i = 0; i < 4; ++i) qv[i] = qs[r * 65 + kk + i];
#pragma unroll
        for (int j = 0; j < 8; ++j) {
            const float4 kv = *(const float4*)(ks + (cg * 8 + j) * 68 + kk);
            sc[j] = fmaf(qv[0], kv.x, sc[j]); sc[j] = fmaf(qv[1], kv.y, sc[j]);
            sc[j] = fmaf(qv[2], kv.z, sc[j]); sc[j] = fmaf(qv[3], kv.w, sc[j]);
        }
    }
    float pm = -1e30f;
#pragma unroll
    for (int j = 0; j < 8; ++j) { sc[j] *= 0.125f; pm = fmaxf(pm, sc[j]); }
    pmax[cg * 64 + r] = pm;
    __syncthreads();
    float m = pmax[r];
#pragma unroll
    for (int i = 1; i < 8; ++i) m = fmaxf(m, pmax[i * 64 + r]);
    float pe[8], ps = 0.f;
#pragma unroll
    for (int j = 0; j < 8; ++j) { pe[j] = __expf(sc[j] - m); ps += pe[j]; }
    psum[cg * 64 + r] = ps;
    __syncthreads();
    float den = psum[r];
#pragma unroll
    for (int i = 1; i < 8; ++i) den += psum[i * 64 + r];
    const float rden = 1.f / den;
#pragma unroll
    for (int j = 0; j < 8; ++j) qs[r * 65 + cg * 8 + j] = pe[j] * rden;  // P overwrites q
    __syncthreads();
    float oa[8];
#pragma unroll
    for (int j = 0; j < 8; ++j) oa[j] = 0.f;
    for (int c = 0; c < 64; ++c) {
        const float pv = qs[r * 65 + c];
        const float4 v0 = *(const float4*)(vs + c * 68 + cg * 8);
        const float4 v1 = *(const float4*)(vs + c * 68 + cg * 8 + 4);
        oa[0] = fmaf(pv, v0.x, oa[0]); oa[1] = fmaf(pv, v0.y, oa[1]);
        oa[2] = fmaf(pv, v0.z, oa[2]); oa[3] = fmaf(pv, v0.w, oa[3]);
        oa[4] = fmaf(pv, v1.x, oa[4]); oa[5] = fmaf(pv, v1.y, oa[5]);
        oa[6] = fmaf(pv, v1.z, oa[6]); oa[7] = fmaf(pv, v1.w, oa[7]);
    }
#pragma unroll
    for (int j = 0; j < 8; ++j) ks[r * 68 + cg * 8 + j] = oa[j];
    __syncthreads();
    for (int idx = t; idx < 4096; idx += 512) {
        const int rr = idx >> 6, dd = idx & 63;
        const float v = ks[rr * 68 + dd];
        unsigned short hh, mm, ll;
        split3(v, hh, mm, ll);
        const size_t o = ((size_t)b * 64 + rr) * 256 + h * 64 + dd;
        oh[o] = hh;
        om[o] = mm;
        ol[o] = ll;
    }
}

// ---------------------------------------------------------------- MFMA GEMM 64-row (be1/be2, split-K)
__global__ __launch_bounds__(256) void k_gemm_mf(
    const unsigned short* __restrict__ Ah, const unsigned short* __restrict__ Am,
    const unsigned short* __restrict__ Al,
    const unsigned short* __restrict__ WP, const float* __restrict__ bias,
    float* __restrict__ Cf, unsigned short* __restrict__ Ch, unsigned short* __restrict__ Cm,
    unsigned short* __restrict__ Cl,
    int M, int N, int K, int kChunk, int relu) {
    const int t = threadIdx.x;
    const int wv = t >> 6, lane = t & 63;
    const int row0 = blockIdx.x * 64 + wv * 16;
    const int col0 = blockIdx.y * 64;
    const int NT = N >> 4;
    const int k0 = blockIdx.z * kChunk;
    const int nks = kChunk >> 5;
    f32x4 acc[4];
#pragma unroll
    for (int nt = 0; nt < 4; ++nt) acc[nt] = (f32x4){0.f, 0.f, 0.f, 0.f};
    const int arow = row0 + (lane & 15);
    const size_t aoff = (size_t)arow * K + k0 + ((lane >> 4) << 3);
    const unsigned short* aph = Ah + aoff;
    const unsigned short* apm = Am + aoff;
    const unsigned short* apl = Al + aoff;
    const unsigned short* bp = WP + ((size_t)((k0 >> 5) * NT + (col0 >> 4))) * 1536 + lane * 8;
    const size_t bstride = (size_t)NT * 1536;
    for (int ks = 0; ks < nks; ++ks) {
        const s16x8 ah = *(const s16x8*)aph;
        const s16x8 am = *(const s16x8*)apm;
        const s16x8 al = *(const s16x8*)apl;
        aph += 32; apm += 32; apl += 32;
#pragma unroll
        for (int nt = 0; nt < 4; ++nt) {
            mfma6(acc[nt], ah, am, al, bp + nt * 1536);
        }
        bp += bstride;
    }
    const int crow = row0 + ((lane >> 4) << 2);
    const int ccol = col0 + (lane & 15);
    float bz[4];
#pragma unroll
    for (int nt = 0; nt < 4; ++nt) bz[nt] = bias ? bias[ccol + nt * 16] : 0.f;
    if (Ch) {
#pragma unroll
        for (int nt = 0; nt < 4; ++nt) {
#pragma unroll
            for (int i = 0; i < 4; ++i) {
                float v = acc[nt][i] + bz[nt];
                if (relu) v = fmaxf(v, 0.f);
                unsigned short hh, mm, ll;
                split3(v, hh, mm, ll);
                const size_t o = (size_t)(crow + i) * N + ccol + nt * 16;
                Ch[o] = hh;
                Cm[o] = mm;
                Cl[o] = ll;
            }
        }
    } else {
        float* base = Cf + (size_t)blockIdx.z * M * N;
#pragma unroll
        for (int nt = 0; nt < 4; ++nt) {
#pragma unroll
            for (int i = 0; i < 4; ++i) {
                float v = acc[nt][i] + bz[nt];
                if (relu) v = fmaxf(v, 0.f);
                base[(size_t)(crow + i) * N + ccol + nt * 16] = v;
            }
        }
    }
}

// ---------------------------------------------------------------- MFMA GEMM 128-row: 32 rows/wave, 48 MFMA / 18 loads per ks
__global__ __launch_bounds__(256) void k_gemm_mf128(
    const unsigned short* __restrict__ Ah, const unsigned short* __restrict__ Am,
    const unsigned short* __restrict__ Al,
    const unsigned short* __restrict__ WP, const float* __restrict__ bias,
    float* __restrict__ Cf, unsigned short* __restrict__ Ch, unsigned short* __restrict__ Cm,
    unsigned short* __restrict__ Cl,
    int M, int N, int K, int relu) {
    const int t = threadIdx.x;
    const int wv = t >> 6, lane = t & 63;
    const int row0 = blockIdx.x * 128 + wv * 32;
    const int col0 = blockIdx.y * 64;
    const int NT = N >> 4;
    const int nks = K >> 5;
    f32x4 acc0[4], acc1[4];
#pragma unroll
    for (int nt = 0; nt < 4; ++nt) {
        acc0[nt] = (f32x4){0.f, 0.f, 0.f, 0.f};
        acc1[nt] = (f32x4){0.f, 0.f, 0.f, 0.f};
    }
    const size_t aoff0 = (size_t)(row0 + (lane & 15)) * K + ((lane >> 4) << 3);
    const size_t aoff1 = aoff0 + (size_t)16 * K;
    const unsigned short* bp = WP + (size_t)(col0 >> 4) * 1536 + lane * 8;
    const size_t bstride = (size_t)NT * 1536;
    for (int ks = 0; ks < nks; ++ks) {
        const size_t ao = ks * 32;
        const s16x8 a0h = *(const s16x8*)(Ah + aoff0 + ao);
        const s16x8 a0m = *(const s16x8*)(Am + aoff0 + ao);
        const s16x8 a0l = *(const s16x8*)(Al + aoff0 + ao);
        const s16x8 a1h = *(const s16x8*)(Ah + aoff1 + ao);
        const s16x8 a1m = *(const s16x8*)(Am + aoff1 + ao);
        const s16x8 a1l = *(const s16x8*)(Al + aoff1 + ao);
#pragma unroll
        for (int nt = 0; nt < 4; ++nt) {
            const unsigned short* bb = bp + nt * 1536;
            const s16x8 bh = *(const s16x8*)(bb);
            const s16x8 bm = *(const s16x8*)(bb + 512);
            const s16x8 bl = *(const s16x8*)(bb + 1024);
            acc0[nt] = MF(a0h, bh, acc0[nt]);
            acc0[nt] = MF(a0h, bm, acc0[nt]);
            acc0[nt] = MF(a0m, bh, acc0[nt]);
            acc0[nt] = MF(a0h, bl, acc0[nt]);
            acc0[nt] = MF(a0l, bh, acc0[nt]);
            acc0[nt] = MF(a0m, bm, acc0[nt]);
            acc1[nt] = MF(a1h, bh, acc1[nt]);
            acc1[nt] = MF(a1h, bm, acc1[nt]);
            acc1[nt] = MF(a1m, bh, acc1[nt]);
            acc1[nt] = MF(a1h, bl, acc1[nt]);
            acc1[nt] = MF(a1l, bh, acc1[nt]);
            acc1[nt] = MF(a1m, bm, acc1[nt]);
        }
        bp += bstride;
    }
    const int crow0 = row0 + ((lane >> 4) << 2);
    const int ccol = col0 + (lane & 15);
    float bz[4];
#pragma unroll
    for (int nt = 0; nt < 4; ++nt) bz[nt] = bias ? bias[ccol + nt * 16] : 0.f;
#pragma unroll
    for (int half = 0; half < 2; ++half) {
        const int crow = crow0 + half * 16;
        f32x4* ac = half ? acc1 : acc0;
        if (Ch) {
#pragma unroll
            for (int nt = 0; nt < 4; ++nt) {
#pragma unroll
                for (int i = 0; i < 4; ++i) {
                    float v = ac[nt][i] + bz[nt];
                    if (relu) v = fmaxf(v, 0.f);
                    unsigned short hh, mm, ll;
                    split3(v, hh, mm, ll);
                    const size_t o = (size_t)(crow + i) * N + ccol + nt * 16;
                    Ch[o] = hh;
                    Cm[o] = mm;
                    Cl[o] = ll;
                }
            }
        } else {
#pragma unroll
            for (int nt = 0; nt < 4; ++nt) {
#pragma unroll
                for (int i = 0; i < 4; ++i) {
                    float v = ac[nt][i] + bz[nt];
                    if (relu) v = fmaxf(v, 0.f);
                    Cf[(size_t)(crow + i) * N + ccol + nt * 16] = v;
                }
            }
        }
    }
}

// ---------------------------------------------------------------- x = LN(x + add); writes fp32 + 3-plane split
__global__ __launch_bounds__(256) void k_ln_add(float* __restrict__ x, const float* __restrict__ add,
                                                const float* __restrict__ g, const float* __restrict__ bta,
                                                unsigned short* __restrict__ sh, unsigned short* __restrict__ sm,
                                                unsigned short* __restrict__ sl) {
    const int t = threadIdx.x;
    const size_t r = (size_t)blockIdx.x * 4 + (t >> 6);
    const int lane = t & 63;
    float4 xv = *(const float4*)(x + r * 256 + lane * 4);
    const float4 av = *(const float4*)(add + r * 256 + lane * 4);
    const float4 v = make_float4(xv.x + av.x, xv.y + av.y, xv.z + av.z, xv.w + av.w);
    float s = v.x + v.y + v.z + v.w;
    float ss = fmaf(v.x, v.x, fmaf(v.y, v.y, fmaf(v.z, v.z, v.w * v.w)));
#pragma unroll
    for (int m = 32; m; m >>= 1) { s += __shfl_xor(s, m); ss += __shfl_xor(ss, m); }
    const float mean = s * (1.f / 256.f);
    const float var = ss * (1.f / 256.f) - mean * mean;
    const float rstd = rsqrtf(var + 1e-5f);
    const float4 g4 = *(const float4*)(g + lane * 4);
    const float4 b4 = *(const float4*)(bta + lane * 4);
    float4 ov;
    ov.x = (v.x - mean) * rstd * g4.x + b4.x;
    ov.y = (v.y - mean) * rstd * g4.y + b4.y;
    ov.z = (v.z - mean) * rstd * g4.z + b4.z;
    ov.w = (v.w - mean) * rstd * g4.w + b4.w;
    *(float4*)(x + r * 256 + lane * 4) = ov;
    const float vv[4] = {ov.x, ov.y, ov.z, ov.w};
    unsigned short hh[4], mm[4], ll[4];
#pragma unroll
    for (int j = 0; j < 4; ++j) split3(vv[j], hh[j], mm[j], ll[j]);
    *(ushort4*)(sh + r * 256 + lane * 4) = make_ushort4(hh[0], hh[1], hh[2], hh[3]);
    *(ushort4*)(sm + r * 256 + lane * 4) = make_ushort4(mm[0], mm[1], mm[2], mm[3]);
    *(ushort4*)(sl + r * 256 + lane * 4) = make_ushort4(ll[0], ll[1], ll[2], ll[3]);
}

// ---------------------------------------------------------------- be1 split-K reduce + bias + relu -> 3-plane split
__global__ void k_be1_reduce(const float* __restrict__ parts, const float* __restrict__ bias,
                             unsigned short* __restrict__ oh, unsigned short* __restrict__ om,
                             unsigned short* __restrict__ ol, int n) {
    const int idx = blockIdx.x * blockDim.x + threadIdx.x;
    if (idx < n) {
        float s = bias[idx & 255];
#pragma unroll
        for (int p = 0; p < 8; ++p) s += parts[(size_t)p * n + idx];
        s = fmaxf(s, 0.f);
        unsigned short hh, mm, ll;
        split3(s, hh, mm, ll);
        oh[idx] = hh;
        om[idx] = mm;
        ol[idx] = ll;
    }
}

// ================================================================ HRM recurrence, MFMA (round-11 structure, unrolled ks)
DEV void splitpass(const float* scr, unsigned short* frag, int t) {
    const int ks = t >> 6, ln = t & 63;
    const int row = ln & 15;
    const int k0 = ks * 32 + ((ln >> 4) << 3);
    const float* s = scr + row * 260 + k0;
    const float4 p = *(const float4*)s;
    const float4 q = *(const float4*)(s + 4);
    const float v[8] = {p.x, p.y, p.z, p.w, q.x, q.y, q.z, q.w};
    split8store(v, frag + (ks * 3) * 512 + ln * 8);
}

template <int KS>
DEV void rungemm(f32x4& a0, f32x4& a1, const unsigned short* __restrict__ WP,
                 const unsigned short* f0, const unsigned short* f1, const unsigned short* f2,
                 int wv, int lane) {
#pragma unroll 4
    for (int ks = 0; ks < KS; ++ks) {
        const unsigned short* fa = (ks < 8) ? f0 : ((ks < 16) ? f1 : f2);
        const int kl = ks & 7;
        const unsigned short* ap = fa + (kl * 3) * 512 + lane * 8;
        const s16x8 ah = *(const s16x8*)(ap);
        const s16x8 am = *(const s16x8*)(ap + 512);
        const s16x8 al = *(const s16x8*)(ap + 1024);
        const unsigned short* bp = WP + (size_t)((ks * 16 + wv * 2) * 3) * 512 + lane * 8;
        mfma6(a0, ah, am, al, bp);
        mfma6(a1, ah, am, al, bp + 1536);
    }
}

DEV void storeC(f32x4 a0, f32x4 a1, const float* __restrict__ bias, float* scr, int wv, int lane) {
    const int rb = (lane >> 4) * 4;
    const int c0 = wv * 32 + (lane & 15);
    const float bz0 = bias[c0];
    const float bz1 = bias[c0 + 16];
    scr[(rb + 0) * 260 + c0] = fmaxf(a0[0] + bz0, 0.f);
    scr[(rb + 1) * 260 + c0] = fmaxf(a0[1] + bz0, 0.f);
    scr[(rb + 2) * 260 + c0] = fmaxf(a0[2] + bz0, 0.f);
    scr[(rb + 3) * 260 + c0] = fmaxf(a0[3] + bz0, 0.f);
    scr[(rb + 0) * 260 + c0 + 16] = fmaxf(a1[0] + bz1, 0.f);
    scr[(rb + 1) * 260 + c0 + 16] = fmaxf(a1[1] + bz1, 0.f);
    scr[(rb + 2) * 260 + c0 + 16] = fmaxf(a1[2] + bz1, 0.f);
    scr[(rb + 3) * 260 + c0 + 16] = fmaxf(a1[3] + bz1, 0.f);
}

DEV void lnpass(float* scr, const float* __restrict__ g, const float* __restrict__ bb, int t) {
    const int row = 2 * (t >> 6) + ((t & 63) >> 5);
    const int c0 = (t & 31) * 8;
    float* s = scr + row * 260 + c0;
    const float4 x0 = *(const float4*)s;
    const float4 x1 = *(const float4*)(s + 4);
    float sum = x0.x + x0.y + x0.z + x0.w + x1.x + x1.y + x1.z + x1.w;
    float sq = fmaf(x0.x, x0.x, fmaf(x0.y, x0.y, fmaf(x0.z, x0.z, x0.w * x0.w)));
    sq = fmaf(x1.x, x1.x, fmaf(x1.y, x1.y, fmaf(x1.z, x1.z, fmaf(x1.w, x1.w, sq))));
#pragma unroll
    for (int m = 16; m; m >>= 1) { sum += __shfl_xor(sum, m); sq += __shfl_xor(sq, m); }
    const float mean = sum * (1.f / 256.f);
    const float var = sq * (1.f / 256.f) - mean * mean;
    const float rstd = rsqrtf(var + 1e-5f);
    const float4 g0 = *(const float4*)(g + c0);
    const float4 g1 = *(const float4*)(g + c0 + 4);
    const float4 b0 = *(const float4*)(bb + c0);
    const float4 b1 = *(const float4*)(bb + c0 + 4);
    float4 o0, o1;
    o0.x = (x0.x - mean) * rstd * g0.x + b0.x;
    o0.y = (x0.y - mean) * rstd * g0.y + b0.y;
    o0.z = (x0.z - mean) * rstd * g0.z + b0.z;
    o0.w = (x0.w - mean) * rstd * g0.w + b0.w;
    o1.x = (x1.x - mean) * rstd * g1.x + b1.x;
    o1.y = (x1.y - mean) * rstd * g1.y + b1.y;
    o1.z = (x1.z - mean) * rstd * g1.z + b1.z;
    o1.w = (x1.w - mean) * rstd * g1.w + b1.w;
    *(float4*)s = o0;
    *(float4*)(s + 4) = o1;
}

__global__ __launch_bounds__(512, 1) void k_hrm(const float* __restrict__ be,
        const unsigned short* __restrict__ L1P, const float* __restrict__ L1b,
        const unsigned short* __restrict__ L2P, const float* __restrict__ L2b,
        const float* __restrict__ Lg, const float* __restrict__ Lbt,
        const unsigned short* __restrict__ H1P, const float* __restrict__ H1b,
        const unsigned short* __restrict__ H2P, const float* __restrict__ H2b,
        const float* __restrict__ Hg, const float* __restrict__ Hbt,
        const unsigned short* __restrict__ v1P, const float* __restrict__ v1b,
        const float* __restrict__ v2T, const float* __restrict__ v2b,
        float* __restrict__ out) {
    __shared__ __align__(16) unsigned short fzL[12288];
    __shared__ __align__(16) unsigned short fzH[12288];
    __shared__ __align__(16) unsigned short fbe[12288];
    __shared__ __align__(16) unsigned short fh1[12288];
    __shared__ __align__(16) float scr[16 * 260];
    const int t = threadIdx.x;
    const int b0 = blockIdx.x * 16;
    const int wv = t >> 6, lane = t & 63;
    for (int i = t; i < 12288; i += 512) { fzL[i] = 0; fzH[i] = 0; }
    {
        const int ks = t >> 6, ln = t & 63;
        const int row = ln & 15;
        const int k0 = ks * 32 + ((ln >> 4) << 3);
        const float* s = be + (size_t)(b0 + row) * 256 + k0;
        const float4 p = *(const float4*)s;
        const float4 q = *(const float4*)(s + 4);
        const float v[8] = {p.x, p.y, p.z, p.w, q.x, q.y, q.z, q.w};
        split8store(v, fbe + (ks * 3) * 512 + ln * 8);
    }
    __syncthreads();
    const f32x4 zero4 = {0.f, 0.f, 0.f, 0.f};
    for (int it = 0; it < 64; ++it) {
        f32x4 a0 = zero4, a1 = zero4;
        rungemm<24>(a0, a1, L1P, fzL, fzH, fbe, wv, lane);
        storeC(a0, a1, L1b, scr, wv, lane);
        __syncthreads();
        splitpass(scr, fh1, t);
        __syncthreads();
        a0 = zero4; a1 = zero4;
        rungemm<8>(a0, a1, L2P, fh1, fh1, fh1, wv, lane);
        storeC(a0, a1, L2b, scr, wv, lane);
        __syncthreads();
        lnpass(scr, Lg, Lbt, t);
        __syncthreads();
        splitpass(scr, fzL, t);
        __syncthreads();
        if (((it + 1) & 7) == 0) {
            a0 = zero4; a1 = zero4;
            rungemm<16>(a0, a1, H1P, fzH, fzL, fzL, wv, lane);
            storeC(a0, a1, H1b, scr, wv, lane);
            __syncthreads();
            splitpass(scr, fh1, t);
            __syncthreads();
            a0 = zero4; a1 = zero4;
            rungemm<8>(a0, a1, H2P, fh1, fh1, fh1, wv, lane);
            storeC(a0, a1, H2b, scr, wv, lane);
            __syncthreads();
            lnpass(scr, Hg, Hbt, t);
            __syncthreads();
            splitpass(scr, fzH, t);
            __syncthreads();
        }
    }
    f32x4 a0 = zero4, a1 = zero4;
    rungemm<8>(a0, a1, v1P, fzH, fzH, fzH, wv, lane);
    storeC(a0, a1, v1b, scr, wv, lane);
    __syncthreads();
    for (int idx = t; idx < 2048; idx += 512) {
        const int r = idx >> 7, oo = idx & 127;
        float s = v2b[oo];
        for (int kk = 0; kk < 256; kk += 4) {
            const float4 c4 = *(const float4*)(&scr[r * 260 + kk]);
            s = fmaf(c4.x, v2T[(kk + 0) * 128 + oo], s);
            s = fmaf(c4.y, v2T[(kk + 1) * 128 + oo], s);
            s = fmaf(c4.z, v2T[(kk + 2) * 128 + oo], s);
            s = fmaf(c4.w, v2T[(kk + 3) * 128 + oo], s);
        }
        out[(size_t)(b0 + r) * 128 + oo] = s;
    }
}

// ================================================================ launch
extern "C" void kernel_launch(void* const* d_in, const int* in_sizes, int n_in,
                              void* d_out, int out_size, void* d_ws, size_t ws_size,
                              hipStream_t stream) {
    const float* bitplanes  = (const float*)d_in[0];
    const float* conv1_w    = (const float*)d_in[1];
    const float* conv1_b    = (const float*)d_in[2];
    const float* conv2_w    = (const float*)d_in[3];
    const float* conv2_b    = (const float*)d_in[4];
    const float* in_proj_w  = (const float*)d_in[5];
    const float* in_proj_b  = (const float*)d_in[6];
    const float* out_proj_w = (const float*)d_in[7];
    const float* out_proj_b = (const float*)d_in[8];
    const float* ln1_g      = (const float*)d_in[9];
    const float* ln1_b      = (const float*)d_in[10];
    const float* ff1_w      = (const float*)d_in[11];
    const float* ff1_b      = (const float*)d_in[12];
    const float* ff2_w      = (const float*)d_in[13];
    const float* ff2_b      = (const float*)d_in[14];
    const float* ln2_g      = (const float*)d_in[15];
    const float* ln2_b      = (const float*)d_in[16];
    const float* be1_w      = (const float*)d_in[17];
    const float* be1_b      = (const float*)d_in[18];
    const float* be2_w      = (const float*)d_in[19];
    const float* be2_b      = (const float*)d_in[20];
    const float* L1_w       = (const float*)d_in[21];
    const float* L1_b       = (const float*)d_in[22];
    const float* L2_w       = (const float*)d_in[23];
    const float* L2_b       = (const float*)d_in[24];
    const float* Lln_g      = (const float*)d_in[25];
    const float* Lln_b      = (const float*)d_in[26];
    const float* H1_w       = (const float*)d_in[27];
    const float* H1_b       = (const float*)d_in[28];
    const float* H2_w       = (const float*)d_in[29];
    const float* H2_b       = (const float*)d_in[30];
    const float* Hln_g      = (const float*)d_in[31];
    const float* Hln_b      = (const float*)d_in[32];
    const float* v1_w       = (const float*)d_in[33];
    const float* v1_b       = (const float*)d_in[34];
    const float* v2_w       = (const float*)d_in[35];
    const float* v2_b       = (const float*)d_in[36];

    // per-chunk floats = CB*106880; persistent tail = 9,404,416 floats
    const size_t persist = 9404416ull;
    int CB = 64;
    for (int c = 2048; c >= 64; c >>= 1) {
        size_t needBytes = ((size_t)c * 106880ull + persist) * 4ull;
        if (needBytes <= ws_size) { CB = c; break; }
    }
    const int NCH = 2048 / CB;

    float* ws = (float*)d_ws;
    float* a1buf = ws;                                  // CB*16384 fp32
    float* xbuf  = a1buf + (size_t)CB * 16384;          // CB*16384 fp32
    float* sbuf  = xbuf + (size_t)CB * 16384;           // CB*24576 fl = 3 bf16 planes CB*64*256
    float* tbuf  = sbuf + (size_t)CB * 24576;           // CB*49152 fl (qkv fp32 / ff1 planes / be1 parts)
    float* bemf  = tbuf + (size_t)CB * 49152;           // CB*384 fl = 3 bf16 planes CB*256
    float* wpQf  = bemf + (size_t)CB * 384;             // 294,912 (in_proj 3-term pack)
    float* v2T   = wpQf + 294912;                       // 32,768
    float* L1Pf  = v2T + 32768;                         // 294,912
    float* L2Pf  = L1Pf + 294912;                       // 98,304
    float* H1Pf  = L2Pf + 98304;                        // 196,608
    float* H2Pf  = H1Pf + 196608;                       // 98,304
    float* v1Pf  = H2Pf + 98304;                        // 98,304
    float* beB   = v1Pf + 98304;                        // 524,288
    float* wpOf  = beB + 524288;                        // 98,304
    float* wpF1f = wpOf + 98304;                        // 196,608
    float* wpF2f = wpF1f + 196608;                      // 196,608
    float* wpB1f = wpF2f + 196608;                      // 6,291,456
    float* wpB2f = wpB1f + 6291456;                     // 98,304
    float* wpC2f = wpB2f + 98304;                       // 884,736

    unsigned short* soh = (unsigned short*)sbuf;
    unsigned short* som = soh + (size_t)CB * 16384;
    unsigned short* sol = som + (size_t)CB * 16384;
    unsigned short* tbh = (unsigned short*)tbuf;
    unsigned short* tbm = tbh + (size_t)CB * 32768;
    unsigned short* tbl = tbm + (size_t)CB * 32768;
    unsigned short* bemh = (unsigned short*)bemf;
    unsigned short* bemm = bemh + (size_t)CB * 256;
    unsigned short* beml = bemm + (size_t)CB * 256;
    unsigned short* wpQ = (unsigned short*)wpQf;
    unsigned short* L1P = (unsigned short*)L1Pf;
    unsigned short* L2P = (unsigned short*)L2Pf;
    unsigned short* H1P = (unsigned short*)H1Pf;
    unsigned short* H2P = (unsigned short*)H2Pf;
    unsigned short* v1P = (unsigned short*)v1Pf;
    unsigned short* wpO = (unsigned short*)wpOf;
    unsigned short* wpF1 = (unsigned short*)wpF1f;
    unsigned short* wpF2 = (unsigned short*)wpF2f;
    unsigned short* wpB1 = (unsigned short*)wpB1f;
    unsigned short* wpB2 = (unsigned short*)wpB2f;
    unsigned short* wpC2 = (unsigned short*)wpC2f;

    // weight prep (once) — all packs 3-term
    k_tpose<<<64, 256, 0, stream>>>(v2_w, v2T, 128, 256);
    k_wpack3<<<96, 256, 0, stream>>>(in_proj_w, wpQ, 256, 48, 256, 1, 0);
    k_wpack3<<<96, 256, 0, stream>>>(L1_w, L1P, 768, 16, 768, 1, 0);
    k_wpack3<<<32, 256, 0, stream>>>(L2_w, L2P, 256, 16, 256, 1, 0);
    k_wpack3<<<64, 256, 0, stream>>>(H1_w, H1P, 512, 16, 512, 1, 0);
    k_wpack3<<<32, 256, 0, stream>>>(H2_w, H2P, 256, 16, 256, 1, 0);
    k_wpack3<<<32, 256, 0, stream>>>(v1_w, v1P, 256, 16, 256, 1, 0);
    k_wpack3<<<32, 256, 0, stream>>>(out_proj_w, wpO, 256, 16, 256, 1, 0);
    k_wpack3<<<64, 256, 0, stream>>>(ff1_w, wpF1, 256, 32, 256, 1, 0);
    k_wpack3<<<64, 256, 0, stream>>>(ff2_w, wpF2, 512, 16, 512, 1, 0);
    k_wpack3<<<2048, 256, 0, stream>>>(be1_w, wpB1, 16384, 16, 16384, 1, 0);
    k_wpack3<<<32, 256, 0, stream>>>(be2_w, wpB2, 256, 16, 256, 1, 0);
    for (int tap = 0; tap < 9; ++tap)
        k_wpack3<<<32, 256, 0, stream>>>(conv2_w, wpC2 + (size_t)tap * 196608, 256, 16, 2304, 9, tap);

    for (int ch = 0; ch < NCH; ++ch) {
        const float* bp_c = bitplanes + (size_t)ch * CB * 20 * 64;
        // conv encoder (conv2 emits x fp32 + split planes)
        k_conv1<<<CB, 256, 0, stream>>>(bp_c, conv1_w, conv1_b, a1buf);
        k_conv2mf<<<CB, 256, 0, stream>>>(a1buf, wpC2, conv2_b, xbuf, soh, som, sol);
        // qkv projection (wide MFMA GEMM) then attention core
        k_gemm_mf128<<<dim3(CB / 2, 12), 256, 0, stream>>>(soh, som, sol, wpQ, in_proj_b,
                                                           tbuf, nullptr, nullptr, nullptr,
                                                           CB * 64, 768, 256, 0);
        k_attn2<<<dim3(CB, 4), 512, 0, stream>>>(tbuf, soh, som, sol);
        k_gemm_mf128<<<dim3(CB / 2, 4), 256, 0, stream>>>(soh, som, sol, wpO, out_proj_b,
                                                          a1buf, nullptr, nullptr, nullptr,
                                                          CB * 64, 256, 256, 0);
        k_ln_add<<<CB * 16, 256, 0, stream>>>(xbuf, a1buf, ln1_g, ln1_b, soh, som, sol);
        k_gemm_mf128<<<dim3(CB / 2, 8), 256, 0, stream>>>(soh, som, sol, wpF1, ff1_b,
                                                          nullptr, tbh, tbm, tbl,
                                                          CB * 64, 512, 256, 1);
        k_gemm_mf128<<<dim3(CB / 2, 4), 256, 0, stream>>>(tbh, tbm, tbl, wpF2, ff2_b,
                                                          a1buf, nullptr, nullptr, nullptr,
                                                          CB * 64, 256, 512, 0);
        k_ln_add<<<CB * 16, 256, 0, stream>>>(xbuf, a1buf, ln2_g, ln2_b, soh, som, sol);
        // board embedding: be = relu(relu(xf@be1^T+b)@be2^T+b)
        k_gemm_mf<<<dim3(CB / 64, 4, 8), 256, 0, stream>>>(soh, som, sol, wpB1, nullptr,
                                                           tbuf, nullptr, nullptr, nullptr,
                                                           CB, 256, 16384, 2048, 0);
        k_be1_reduce<<<CB, 256, 0, stream>>>(tbuf, be1_b, bemh, bemm, beml, CB * 256);
        k_gemm_mf<<<dim3(CB / 64, 4, 1), 256, 0, stream>>>(bemh, bemm, beml, wpB2, be2_b,
                                                           beB + (size_t)ch * CB * 256, nullptr, nullptr, nullptr,
                                                           CB, 256, 256, 256, 1);
    }

    // HRM recurrence + head (MFMA, 128 blocks x 16 rows, r11 structure + unrolled ks)
    k_hrm<<<128, 512, 0, stream>>>(beB, L1P, L1_b, L2P, L2_b, Lln_g, Lln_b,
                                   H1P, H1_b, H2P, H2_b, Hln_g, Hln_b,
                                   v1P, v1_b, v2T, v2_b, (float*)d_out);
}

// Round 15
// 4863.142 us; speedup vs baseline: 1.0881x; 1.0248x over previous
//
#include <hip/hip_runtime.h>
#include <hip/hip_bf16.h>
#include <math.h>

#define DEV __device__ __forceinline__

typedef __attribute__((ext_vector_type(8))) short s16x8;
typedef __attribute__((ext_vector_type(4))) float f32x4;

DEV f32x4 MF(s16x8 a, s16x8 b, f32x4 c) {
    return __builtin_amdgcn_mfma_f32_16x16x32_bf16(a, b, c, 0, 0, 0);
}

// 3-term bf16 split (exact truncation residuals): x = h + m + l + O(2^-24 x)
DEV void split3(float x, unsigned short& h, unsigned short& m, unsigned short& l) {
    const unsigned u = __float_as_uint(x);
    h = (unsigned short)(u >> 16);
    const float r1 = x - __uint_as_float(u & 0xffff0000u);
    const unsigned u1 = __float_as_uint(r1);
    m = (unsigned short)(u1 >> 16);
    const float r2 = r1 - __uint_as_float(u1 & 0xffff0000u);
    l = (unsigned short)(__float_as_uint(r2) >> 16);
}

DEV void split8store(const float v[8], unsigned short* d) {
    s16x8 vh, vm, vl;
#pragma unroll
    for (int j = 0; j < 8; ++j) {
        unsigned short h, m, l;
        split3(v[j], h, m, l);
        vh[j] = (short)h; vm[j] = (short)m; vl[j] = (short)l;
    }
    *(s16x8*)(d) = vh;
    *(s16x8*)(d + 512) = vm;
    *(s16x8*)(d + 1024) = vl;
}

DEV void mfma6(f32x4& acc, s16x8 ah, s16x8 am, s16x8 al, const unsigned short* bp) {
    const s16x8 bh = *(const s16x8*)(bp);
    const s16x8 bm = *(const s16x8*)(bp + 512);
    const s16x8 bl = *(const s16x8*)(bp + 1024);
    acc = MF(ah, bh, acc);
    acc = MF(ah, bm, acc);
    acc = MF(am, bh, acc);
    acc = MF(ah, bl, acc);
    acc = MF(al, bh, acc);
    acc = MF(am, bm, acc);
}

// ---------------------------------------------------------------- transpose: [N][K] -> [K][N]
__global__ void k_tpose(const float* __restrict__ in, float* __restrict__ out, int N, int K) {
    int total = N * K;
    for (int idx = blockIdx.x * blockDim.x + threadIdx.x; idx < total; idx += gridDim.x * blockDim.x) {
        int n = idx / K, k = idx - n * K;
        out[k * N + n] = in[idx];
    }
}

// ---------------------------------------------------------------- 3-term B-frag pack, strided source
__global__ void k_wpack3(const float* __restrict__ W, unsigned short* __restrict__ WP,
                         int K, int NT, int ldw, int stride, int off) {
    const int idx = blockIdx.x * 256 + threadIdx.x;
    const int total = (K >> 5) * NT * 64;
    if (idx >= total) return;
    const int lane = idx & 63;
    const int nt = (idx >> 6) % NT;
    const int ks = idx / (64 * NT);
    const int col = nt * 16 + (lane & 15);
    const int k0 = ks * 32 + ((lane >> 4) << 3);
    const float* src = W + (size_t)col * ldw + (size_t)k0 * stride + off;
    float v[8];
#pragma unroll
    for (int j = 0; j < 8; ++j) v[j] = src[j * stride];
    split8store(v, WP + (size_t)((ks * NT + nt) * 3) * 512 + lane * 8);
}

// ---------------------------------------------------------------- conv1: [CB,20,8,8] -> a1 [CB,64,256], relu
__global__ __launch_bounds__(256) void k_conv1(const float* __restrict__ in, const float* __restrict__ w,
                                               const float* __restrict__ bias, float* __restrict__ out) {
    __shared__ __align__(16) float img[20 * 100];
    __shared__ __align__(16) float stg[16 * 260];
    const int b = blockIdx.x;
    const int t = threadIdx.x;
    for (int idx = t; idx < 2000; idx += 256) {
        int c = idx / 100, pp = idx - c * 100;
        int y = pp / 10, x = pp - y * 10;
        float v = 0.f;
        if (y >= 1 && y <= 8 && x >= 1 && x <= 8)
            v = in[((size_t)b * 20 + c) * 64 + (y - 1) * 8 + (x - 1)];
        img[idx] = v;
    }
    __syncthreads();
    const int oc = t;
    float acc[64];
    const float bz = bias[oc];
#pragma unroll
    for (int p = 0; p < 64; ++p) acc[p] = bz;
    const float* wrow = w + oc * 180;
    for (int c = 0; c < 20; ++c) {
#pragma unroll
        for (int k = 0; k < 9; ++k) {
            const int ky = k / 3, kx = k - ky * 3;
            const float wv = wrow[c * 9 + k];
            const int base = c * 100 + ky * 10 + kx;
#pragma unroll
            for (int p = 0; p < 64; ++p)
                acc[p] = fmaf(wv, img[base + p + ((p >> 3) << 1)], acc[p]);
        }
    }
#pragma unroll
    for (int cc = 0; cc < 4; ++cc) {
        __syncthreads();
#pragma unroll
        for (int p = 0; p < 16; ++p) stg[p * 260 + t] = acc[cc * 16 + p];
        __syncthreads();
        for (int idx = t; idx < 4096; idx += 256) {
            const int r = idx >> 8, c = idx & 255;
            out[((size_t)b * 64 + cc * 16 + r) * 256 + c] = fmaxf(stg[r * 260 + c], 0.f);
        }
    }
}

// ---------------------------------------------------------------- conv2 MFMA (3-term) + split-plane epilogue
__global__ __launch_bounds__(256) void k_conv2mf(const float* __restrict__ a1,
                                                 const unsigned short* __restrict__ WPC2,
                                                 const float* __restrict__ bias,
                                                 float* __restrict__ xout,
                                                 unsigned short* __restrict__ xh,
                                                 unsigned short* __restrict__ xm,
                                                 unsigned short* __restrict__ xl) {
    __shared__ __align__(16) unsigned short AhS[100 * 132];
    __shared__ __align__(16) unsigned short AmS[100 * 132];
    __shared__ __align__(16) unsigned short AlS[100 * 132];
    const int b = blockIdx.x, t = threadIdx.x;
    const int wv = t >> 6, lane = t & 63;
    f32x4 acc[16];
#pragma unroll
    for (int nt = 0; nt < 16; ++nt) acc[nt] = (f32x4){0.f, 0.f, 0.f, 0.f};
    const int pl = lane & 15;
    const int py = pl >> 3, px = pl & 7;
    const int akoff = (lane >> 4) << 3;
    for (int h = 0; h < 2; ++h) {
        __syncthreads();
        for (int idx = t; idx < 12800; idx += 256) {
            const int pr = idx >> 7, c = idx & 127;
            const int Y = pr / 10, X = pr - Y * 10;
            float v = 0.f;
            if (Y >= 1 && Y <= 8 && X >= 1 && X <= 8)
                v = a1[((size_t)b * 64 + (Y - 1) * 8 + X - 1) * 256 + h * 128 + c];
            unsigned short hh, mm, ll;
            split3(v, hh, mm, ll);
            AhS[pr * 132 + c] = hh;
            AmS[pr * 132 + c] = mm;
            AlS[pr * 132 + c] = ll;
        }
        __syncthreads();
#pragma unroll
        for (int tap = 0; tap < 9; ++tap) {
            const int dy = tap / 3, dx = tap - dy * 3;
            const int prow = (wv * 2 + py + dy) * 10 + px + dx;
            const unsigned short* arh = AhS + prow * 132 + akoff;
            const unsigned short* arm = AmS + prow * 132 + akoff;
            const unsigned short* arl = AlS + prow * 132 + akoff;
#pragma unroll
            for (int ks = 0; ks < 4; ++ks) {
                const s16x8 ah = *(const s16x8*)(arh + ks * 32);
                const s16x8 am = *(const s16x8*)(arm + ks * 32);
                const s16x8 al = *(const s16x8*)(arl + ks * 32);
                const unsigned short* bp = WPC2 + (size_t)(tap * 128 + (h * 4 + ks) * 16) * 1536 + lane * 8;
#pragma unroll
                for (int nt = 0; nt < 16; ++nt) {
                    mfma6(acc[nt], ah, am, al, bp + nt * 1536);
                }
            }
        }
    }
    const int prow0 = wv * 16 + ((lane >> 4) << 2);
    const int ccol = lane & 15;
#pragma unroll
    for (int nt = 0; nt < 16; ++nt) {
        const float bz = bias[nt * 16 + ccol];
#pragma unroll
        for (int i = 0; i < 4; ++i) {
            const float v = fmaxf(acc[nt][i] + bz, 0.f);
            const size_t o = ((size_t)b * 64 + prow0 + i) * 256 + nt * 16 + ccol;
            xout[o] = v;
            unsigned short hh, mm, ll;
            split3(v, hh, mm, ll);
            xh[o] = hh;
            xm[o] = mm;
            xl[o] = ll;
        }
    }
}

// ---------------------------------------------------------------- attention core per (b, head): qkv fp32 in, o splits out
__global__ __launch_bounds__(512) void k_attn2(const float* __restrict__ qkv,
                                               unsigned short* __restrict__ oh, unsigned short* __restrict__ om,
                                               unsigned short* __restrict__ ol) {
    __shared__ __align__(16) float qs[64 * 65];  // q, then reused for P
    __shared__ __align__(16) float ks[64 * 68];  // k, then reused for output staging
    __shared__ __align__(16) float vs[64 * 68];
    __shared__ float pmax[8 * 64];
    __shared__ float psum[8 * 64];
    const int b = blockIdx.x, h = blockIdx.y;
    const int t = threadIdx.x;
    for (int idx = t; idx < 1024; idx += 512) {
        const int rr = idx >> 4, cc = (idx & 15) * 4;
        const float* src = qkv + ((size_t)b * 64 + rr) * 768 + h * 64 + cc;
        const float4 q4 = *(const float4*)(src);
        const float4 k4 = *(const float4*)(src + 256);
        const float4 v4 = *(const float4*)(src + 512);
        qs[rr * 65 + cc + 0] = q4.x; qs[rr * 65 + cc + 1] = q4.y;
        qs[rr * 65 + cc + 2] = q4.z; qs[rr * 65 + cc + 3] = q4.w;
        *(float4*)(ks + rr * 68 + cc) = k4;
        *(float4*)(vs + rr * 68 + cc) = v4;
    }
    __syncthreads();
    const int r = t & 63;
    const int cg = t >> 6;
    float sc[8];
#pragma unroll
    for (int j = 0; j < 8; ++j) sc[j] = 0.f;
    for (int kk = 0; kk < 64; kk += 4) {
        float qv[4];
#pragma unroll
        for (int i = 0; i < 4; ++i) qv[i] = qs[r * 65 + kk + i];
#pragma unroll
        for (int j = 0; j < 8; ++j) {
            const float4 kv = *(const float4*)(ks + (cg * 8 + j) * 68 + kk);
            sc[j] = fmaf(qv[0], kv.x, sc[j]); sc[j] = fmaf(qv[1], kv.y, sc[j]);
            sc[j] = fmaf(qv[2], kv.z, sc[j]); sc[j] = fmaf(qv[3], kv.w, sc[j]);
        }
    }
    float pm = -1e30f;
#pragma unroll
    for (int j = 0; j < 8; ++j) { sc[j] *= 0.125f; pm = fmaxf(pm, sc[j]); }
    pmax[cg * 64 + r] = pm;
    __syncthreads();
    float m = pmax[r];
#pragma unroll
    for (int i = 1; i < 8; ++i) m = fmaxf(m, pmax[i * 64 + r]);
    float pe[8], ps = 0.f;
#pragma unroll
    for (int j = 0; j < 8; ++j) { pe[j] = __expf(sc[j] - m); ps += pe[j]; }
    psum[cg * 64 + r] = ps;
    __syncthreads();
    float den = psum[r];
#pragma unroll
    for (int i = 1; i < 8; ++i) den += psum[i * 64 + r];
    const float rden = 1.f / den;
#pragma unroll
    for (int j = 0; j < 8; ++j) qs[r * 65 + cg * 8 + j] = pe[j] * rden;  // P overwrites q
    __syncthreads();
    float oa[8];
#pragma unroll
    for (int j = 0; j < 8; ++j) oa[j] = 0.f;
    for (int c = 0; c < 64; ++c) {
        const float pv = qs[r * 65 + c];
        const float4 v0 = *(const float4*)(vs + c * 68 + cg * 8);
        const float4 v1 = *(const float4*)(vs + c * 68 + cg * 8 + 4);
        oa[0] = fmaf(pv, v0.x, oa[0]); oa[1] = fmaf(pv, v0.y, oa[1]);
        oa[2] = fmaf(pv, v0.z, oa[2]); oa[3] = fmaf(pv, v0.w, oa[3]);
        oa[4] = fmaf(pv, v1.x, oa[4]); oa[5] = fmaf(pv, v1.y, oa[5]);
        oa[6] = fmaf(pv, v1.z, oa[6]); oa[7] = fmaf(pv, v1.w, oa[7]);
    }
#pragma unroll
    for (int j = 0; j < 8; ++j) ks[r * 68 + cg * 8 + j] = oa[j];
    __syncthreads();
    for (int idx = t; idx < 4096; idx += 512) {
        const int rr = idx >> 6, dd = idx & 63;
        const float v = ks[rr * 68 + dd];
        unsigned short hh, mm, ll;
        split3(v, hh, mm, ll);
        const size_t o = ((size_t)b * 64 + rr) * 256 + h * 64 + dd;
        oh[o] = hh;
        om[o] = mm;
        ol[o] = ll;
    }
}

// ---------------------------------------------------------------- MFMA GEMM 64-row (be1/be2, split-K), unrolled ks
__global__ __launch_bounds__(256) void k_gemm_mf(
    const unsigned short* __restrict__ Ah, const unsigned short* __restrict__ Am,
    const unsigned short* __restrict__ Al,
    const unsigned short* __restrict__ WP, const float* __restrict__ bias,
    float* __restrict__ Cf, unsigned short* __restrict__ Ch, unsigned short* __restrict__ Cm,
    unsigned short* __restrict__ Cl,
    int M, int N, int K, int kChunk, int relu) {
    const int t = threadIdx.x;
    const int wv = t >> 6, lane = t & 63;
    const int row0 = blockIdx.x * 64 + wv * 16;
    const int col0 = blockIdx.y * 64;
    const int NT = N >> 4;
    const int k0 = blockIdx.z * kChunk;
    const int nks = kChunk >> 5;
    f32x4 acc[4];
#pragma unroll
    for (int nt = 0; nt < 4; ++nt) acc[nt] = (f32x4){0.f, 0.f, 0.f, 0.f};
    const int arow = row0 + (lane & 15);
    const size_t aoff = (size_t)arow * K + k0 + ((lane >> 4) << 3);
    const unsigned short* aph = Ah + aoff;
    const unsigned short* apm = Am + aoff;
    const unsigned short* apl = Al + aoff;
    const unsigned short* bp = WP + ((size_t)((k0 >> 5) * NT + (col0 >> 4))) * 1536 + lane * 8;
    const size_t bstride = (size_t)NT * 1536;
#pragma unroll 4
    for (int ks = 0; ks < nks; ++ks) {
        const s16x8 ah = *(const s16x8*)(aph + ks * 32);
        const s16x8 am = *(const s16x8*)(apm + ks * 32);
        const s16x8 al = *(const s16x8*)(apl + ks * 32);
        const unsigned short* bb0 = bp + (size_t)ks * bstride;
#pragma unroll
        for (int nt = 0; nt < 4; ++nt) {
            mfma6(acc[nt], ah, am, al, bb0 + nt * 1536);
        }
    }
    const int crow = row0 + ((lane >> 4) << 2);
    const int ccol = col0 + (lane & 15);
    float bz[4];
#pragma unroll
    for (int nt = 0; nt < 4; ++nt) bz[nt] = bias ? bias[ccol + nt * 16] : 0.f;
    if (Ch) {
#pragma unroll
        for (int nt = 0; nt < 4; ++nt) {
#pragma unroll
            for (int i = 0; i < 4; ++i) {
                float v = acc[nt][i] + bz[nt];
                if (relu) v = fmaxf(v, 0.f);
                unsigned short hh, mm, ll;
                split3(v, hh, mm, ll);
                const size_t o = (size_t)(crow + i) * N + ccol + nt * 16;
                Ch[o] = hh;
                Cm[o] = mm;
                Cl[o] = ll;
            }
        }
    } else {
        float* base = Cf + (size_t)blockIdx.z * M * N;
#pragma unroll
        for (int nt = 0; nt < 4; ++nt) {
#pragma unroll
            for (int i = 0; i < 4; ++i) {
                float v = acc[nt][i] + bz[nt];
                if (relu) v = fmaxf(v, 0.f);
                base[(size_t)(crow + i) * N + ccol + nt * 16] = v;
            }
        }
    }
}

// ---------------------------------------------------------------- MFMA GEMM 128-row: 32 rows/wave, unrolled ks
__global__ __launch_bounds__(256) void k_gemm_mf128(
    const unsigned short* __restrict__ Ah, const unsigned short* __restrict__ Am,
    const unsigned short* __restrict__ Al,
    const unsigned short* __restrict__ WP, const float* __restrict__ bias,
    float* __restrict__ Cf, unsigned short* __restrict__ Ch, unsigned short* __restrict__ Cm,
    unsigned short* __restrict__ Cl,
    int M, int N, int K, int relu) {
    const int t = threadIdx.x;
    const int wv = t >> 6, lane = t & 63;
    const int row0 = blockIdx.x * 128 + wv * 32;
    const int col0 = blockIdx.y * 64;
    const int NT = N >> 4;
    const int nks = K >> 5;
    f32x4 acc0[4], acc1[4];
#pragma unroll
    for (int nt = 0; nt < 4; ++nt) {
        acc0[nt] = (f32x4){0.f, 0.f, 0.f, 0.f};
        acc1[nt] = (f32x4){0.f, 0.f, 0.f, 0.f};
    }
    const size_t aoff0 = (size_t)(row0 + (lane & 15)) * K + ((lane >> 4) << 3);
    const size_t aoff1 = aoff0 + (size_t)16 * K;
    const unsigned short* bp = WP + (size_t)(col0 >> 4) * 1536 + lane * 8;
    const size_t bstride = (size_t)NT * 1536;
#pragma unroll 4
    for (int ks = 0; ks < nks; ++ks) {
        const size_t ao = (size_t)ks * 32;
        const s16x8 a0h = *(const s16x8*)(Ah + aoff0 + ao);
        const s16x8 a0m = *(const s16x8*)(Am + aoff0 + ao);
        const s16x8 a0l = *(const s16x8*)(Al + aoff0 + ao);
        const s16x8 a1h = *(const s16x8*)(Ah + aoff1 + ao);
        const s16x8 a1m = *(const s16x8*)(Am + aoff1 + ao);
        const s16x8 a1l = *(const s16x8*)(Al + aoff1 + ao);
        const unsigned short* bb0 = bp + (size_t)ks * bstride;
#pragma unroll
        for (int nt = 0; nt < 4; ++nt) {
            const unsigned short* bb = bb0 + nt * 1536;
            const s16x8 bh = *(const s16x8*)(bb);
            const s16x8 bm = *(const s16x8*)(bb + 512);
            const s16x8 bl = *(const s16x8*)(bb + 1024);
            acc0[nt] = MF(a0h, bh, acc0[nt]);
            acc0[nt] = MF(a0h, bm, acc0[nt]);
            acc0[nt] = MF(a0m, bh, acc0[nt]);
            acc0[nt] = MF(a0h, bl, acc0[nt]);
            acc0[nt] = MF(a0l, bh, acc0[nt]);
            acc0[nt] = MF(a0m, bm, acc0[nt]);
            acc1[nt] = MF(a1h, bh, acc1[nt]);
            acc1[nt] = MF(a1h, bm, acc1[nt]);
            acc1[nt] = MF(a1m, bh, acc1[nt]);
            acc1[nt] = MF(a1h, bl, acc1[nt]);
            acc1[nt] = MF(a1l, bh, acc1[nt]);
            acc1[nt] = MF(a1m, bm, acc1[nt]);
        }
    }
    const int crow0 = row0 + ((lane >> 4) << 2);
    const int ccol = col0 + (lane & 15);
    float bz[4];
#pragma unroll
    for (int nt = 0; nt < 4; ++nt) bz[nt] = bias ? bias[ccol + nt * 16] : 0.f;
#pragma unroll
    for (int half = 0; half < 2; ++half) {
        const int crow = crow0 + half * 16;
        f32x4* ac = half ? acc1 : acc0;
        if (Ch) {
#pragma unroll
            for (int nt = 0; nt < 4; ++nt) {
#pragma unroll
                for (int i = 0; i < 4; ++i) {
                    float v = ac[nt][i] + bz[nt];
                    if (relu) v = fmaxf(v, 0.f);
                    unsigned short hh, mm, ll;
                    split3(v, hh, mm, ll);
                    const size_t o = (size_t)(crow + i) * N + ccol + nt * 16;
                    Ch[o] = hh;
                    Cm[o] = mm;
                    Cl[o] = ll;
                }
            }
        } else {
#pragma unroll
            for (int nt = 0; nt < 4; ++nt) {
#pragma unroll
                for (int i = 0; i < 4; ++i) {
                    float v = ac[nt][i] + bz[nt];
                    if (relu) v = fmaxf(v, 0.f);
                    Cf[(size_t)(crow + i) * N + ccol + nt * 16] = v;
                }
            }
        }
    }
}

// ---------------------------------------------------------------- x = LN(x + add); writes fp32 + 3-plane split
__global__ __launch_bounds__(256) void k_ln_add(float* __restrict__ x, const float* __restrict__ add,
                                                const float* __restrict__ g, const float* __restrict__ bta,
                                                unsigned short* __restrict__ sh, unsigned short* __restrict__ sm,
                                                unsigned short* __restrict__ sl) {
    const int t = threadIdx.x;
    const size_t r = (size_t)blockIdx.x * 4 + (t >> 6);
    const int lane = t & 63;
    float4 xv = *(const float4*)(x + r * 256 + lane * 4);
    const float4 av = *(const float4*)(add + r * 256 + lane * 4);
    const float4 v = make_float4(xv.x + av.x, xv.y + av.y, xv.z + av.z, xv.w + av.w);
    float s = v.x + v.y + v.z + v.w;
    float ss = fmaf(v.x, v.x, fmaf(v.y, v.y, fmaf(v.z, v.z, v.w * v.w)));
#pragma unroll
    for (int m = 32; m; m >>= 1) { s += __shfl_xor(s, m); ss += __shfl_xor(ss, m); }
    const float mean = s * (1.f / 256.f);
    const float var = ss * (1.f / 256.f) - mean * mean;
    const float rstd = rsqrtf(var + 1e-5f);
    const float4 g4 = *(const float4*)(g + lane * 4);
    const float4 b4 = *(const float4*)(bta + lane * 4);
    float4 ov;
    ov.x = (v.x - mean) * rstd * g4.x + b4.x;
    ov.y = (v.y - mean) * rstd * g4.y + b4.y;
    ov.z = (v.z - mean) * rstd * g4.z + b4.z;
    ov.w = (v.w - mean) * rstd * g4.w + b4.w;
    *(float4*)(x + r * 256 + lane * 4) = ov;
    const float vv[4] = {ov.x, ov.y, ov.z, ov.w};
    unsigned short hh[4], mm[4], ll[4];
#pragma unroll
    for (int j = 0; j < 4; ++j) split3(vv[j], hh[j], mm[j], ll[j]);
    *(ushort4*)(sh + r * 256 + lane * 4) = make_ushort4(hh[0], hh[1], hh[2], hh[3]);
    *(ushort4*)(sm + r * 256 + lane * 4) = make_ushort4(mm[0], mm[1], mm[2], mm[3]);
    *(ushort4*)(sl + r * 256 + lane * 4) = make_ushort4(ll[0], ll[1], ll[2], ll[3]);
}

// ---------------------------------------------------------------- be1 split-K reduce + bias + relu -> 3-plane split
__global__ void k_be1_reduce(const float* __restrict__ parts, const float* __restrict__ bias,
                             unsigned short* __restrict__ oh, unsigned short* __restrict__ om,
                             unsigned short* __restrict__ ol, int n) {
    const int idx = blockIdx.x * blockDim.x + threadIdx.x;
    if (idx < n) {
        float s = bias[idx & 255];
#pragma unroll
        for (int p = 0; p < 8; ++p) s += parts[(size_t)p * n + idx];
        s = fmaxf(s, 0.f);
        unsigned short hh, mm, ll;
        split3(s, hh, mm, ll);
        oh[idx] = hh;
        om[idx] = mm;
        ol[idx] = ll;
    }
}

// ================================================================ HRM recurrence, MFMA (round-14 verified, unchanged)
DEV void splitpass(const float* scr, unsigned short* frag, int t) {
    const int ks = t >> 6, ln = t & 63;
    const int row = ln & 15;
    const int k0 = ks * 32 + ((ln >> 4) << 3);
    const float* s = scr + row * 260 + k0;
    const float4 p = *(const float4*)s;
    const float4 q = *(const float4*)(s + 4);
    const float v[8] = {p.x, p.y, p.z, p.w, q.x, q.y, q.z, q.w};
    split8store(v, frag + (ks * 3) * 512 + ln * 8);
}

template <int KS>
DEV void rungemm(f32x4& a0, f32x4& a1, const unsigned short* __restrict__ WP,
                 const unsigned short* f0, const unsigned short* f1, const unsigned short* f2,
                 int wv, int lane) {
#pragma unroll 4
    for (int ks = 0; ks < KS; ++ks) {
        const unsigned short* fa = (ks < 8) ? f0 : ((ks < 16) ? f1 : f2);
        const int kl = ks & 7;
        const unsigned short* ap = fa + (kl * 3) * 512 + lane * 8;
        const s16x8 ah = *(const s16x8*)(ap);
        const s16x8 am = *(const s16x8*)(ap + 512);
        const s16x8 al = *(const s16x8*)(ap + 1024);
        const unsigned short* bp = WP + (size_t)((ks * 16 + wv * 2) * 3) * 512 + lane * 8;
        mfma6(a0, ah, am, al, bp);
        mfma6(a1, ah, am, al, bp + 1536);
    }
}

DEV void storeC(f32x4 a0, f32x4 a1, const float* __restrict__ bias, float* scr, int wv, int lane) {
    const int rb = (lane >> 4) * 4;
    const int c0 = wv * 32 + (lane & 15);
    const float bz0 = bias[c0];
    const float bz1 = bias[c0 + 16];
    scr[(rb + 0) * 260 + c0] = fmaxf(a0[0] + bz0, 0.f);
    scr[(rb + 1) * 260 + c0] = fmaxf(a0[1] + bz0, 0.f);
    scr[(rb + 2) * 260 + c0] = fmaxf(a0[2] + bz0, 0.f);
    scr[(rb + 3) * 260 + c0] = fmaxf(a0[3] + bz0, 0.f);
    scr[(rb + 0) * 260 + c0 + 16] = fmaxf(a1[0] + bz1, 0.f);
    scr[(rb + 1) * 260 + c0 + 16] = fmaxf(a1[1] + bz1, 0.f);
    scr[(rb + 2) * 260 + c0 + 16] = fmaxf(a1[2] + bz1, 0.f);
    scr[(rb + 3) * 260 + c0 + 16] = fmaxf(a1[3] + bz1, 0.f);
}

DEV void lnpass(float* scr, const float* __restrict__ g, const float* __restrict__ bb, int t) {
    const int row = 2 * (t >> 6) + ((t & 63) >> 5);
    const int c0 = (t & 31) * 8;
    float* s = scr + row * 260 + c0;
    const float4 x0 = *(const float4*)s;
    const float4 x1 = *(const float4*)(s + 4);
    float sum = x0.x + x0.y + x0.z + x0.w + x1.x + x1.y + x1.z + x1.w;
    float sq = fmaf(x0.x, x0.x, fmaf(x0.y, x0.y, fmaf(x0.z, x0.z, x0.w * x0.w)));
    sq = fmaf(x1.x, x1.x, fmaf(x1.y, x1.y, fmaf(x1.z, x1.z, fmaf(x1.w, x1.w, sq))));
#pragma unroll
    for (int m = 16; m; m >>= 1) { sum += __shfl_xor(sum, m); sq += __shfl_xor(sq, m); }
    const float mean = sum * (1.f / 256.f);
    const float var = sq * (1.f / 256.f) - mean * mean;
    const float rstd = rsqrtf(var + 1e-5f);
    const float4 g0 = *(const float4*)(g + c0);
    const float4 g1 = *(const float4*)(g + c0 + 4);
    const float4 b0 = *(const float4*)(bb + c0);
    const float4 b1 = *(const float4*)(bb + c0 + 4);
    float4 o0, o1;
    o0.x = (x0.x - mean) * rstd * g0.x + b0.x;
    o0.y = (x0.y - mean) * rstd * g0.y + b0.y;
    o0.z = (x0.z - mean) * rstd * g0.z + b0.z;
    o0.w = (x0.w - mean) * rstd * g0.w + b0.w;
    o1.x = (x1.x - mean) * rstd * g1.x + b1.x;
    o1.y = (x1.y - mean) * rstd * g1.y + b1.y;
    o1.z = (x1.z - mean) * rstd * g1.z + b1.z;
    o1.w = (x1.w - mean) * rstd * g1.w + b1.w;
    *(float4*)s = o0;
    *(float4*)(s + 4) = o1;
}

__global__ __launch_bounds__(512, 1) void k_hrm(const float* __restrict__ be,
        const unsigned short* __restrict__ L1P, const float* __restrict__ L1b,
        const unsigned short* __restrict__ L2P, const float* __restrict__ L2b,
        const float* __restrict__ Lg, const float* __restrict__ Lbt,
        const unsigned short* __restrict__ H1P, const float* __restrict__ H1b,
        const unsigned short* __restrict__ H2P, const float* __restrict__ H2b,
        const float* __restrict__ Hg, const float* __restrict__ Hbt,
        const unsigned short* __restrict__ v1P, const float* __restrict__ v1b,
        const float* __restrict__ v2T, const float* __restrict__ v2b,
        float* __restrict__ out) {
    __shared__ __align__(16) unsigned short fzL[12288];
    __shared__ __align__(16) unsigned short fzH[12288];
    __shared__ __align__(16) unsigned short fbe[12288];
    __shared__ __align__(16) unsigned short fh1[12288];
    __shared__ __align__(16) float scr[16 * 260];
    const int t = threadIdx.x;
    const int b0 = blockIdx.x * 16;
    const int wv = t >> 6, lane = t & 63;
    for (int i = t; i < 12288; i += 512) { fzL[i] = 0; fzH[i] = 0; }
    {
        const int ks = t >> 6, ln = t & 63;
        const int row = ln & 15;
        const int k0 = ks * 32 + ((ln >> 4) << 3);
        const float* s = be + (size_t)(b0 + row) * 256 + k0;
        const float4 p = *(const float4*)s;
        const float4 q = *(const float4*)(s + 4);
        const float v[8] = {p.x, p.y, p.z, p.w, q.x, q.y, q.z, q.w};
        split8store(v, fbe + (ks * 3) * 512 + ln * 8);
    }
    __syncthreads();
    const f32x4 zero4 = {0.f, 0.f, 0.f, 0.f};
    for (int it = 0; it < 64; ++it) {
        f32x4 a0 = zero4, a1 = zero4;
        rungemm<24>(a0, a1, L1P, fzL, fzH, fbe, wv, lane);
        storeC(a0, a1, L1b, scr, wv, lane);
        __syncthreads();
        splitpass(scr, fh1, t);
        __syncthreads();
        a0 = zero4; a1 = zero4;
        rungemm<8>(a0, a1, L2P, fh1, fh1, fh1, wv, lane);
        storeC(a0, a1, L2b, scr, wv, lane);
        __syncthreads();
        lnpass(scr, Lg, Lbt, t);
        __syncthreads();
        splitpass(scr, fzL, t);
        __syncthreads();
        if (((it + 1) & 7) == 0) {
            a0 = zero4; a1 = zero4;
            rungemm<16>(a0, a1, H1P, fzH, fzL, fzL, wv, lane);
            storeC(a0, a1, H1b, scr, wv, lane);
            __syncthreads();
            splitpass(scr, fh1, t);
            __syncthreads();
            a0 = zero4; a1 = zero4;
            rungemm<8>(a0, a1, H2P, fh1, fh1, fh1, wv, lane);
            storeC(a0, a1, H2b, scr, wv, lane);
            __syncthreads();
            lnpass(scr, Hg, Hbt, t);
            __syncthreads();
            splitpass(scr, fzH, t);
            __syncthreads();
        }
    }
    f32x4 a0 = zero4, a1 = zero4;
    rungemm<8>(a0, a1, v1P, fzH, fzH, fzH, wv, lane);
    storeC(a0, a1, v1b, scr, wv, lane);
    __syncthreads();
    for (int idx = t; idx < 2048; idx += 512) {
        const int r = idx >> 7, oo = idx & 127;
        float s = v2b[oo];
        for (int kk = 0; kk < 256; kk += 4) {
            const float4 c4 = *(const float4*)(&scr[r * 260 + kk]);
            s = fmaf(c4.x, v2T[(kk + 0) * 128 + oo], s);
            s = fmaf(c4.y, v2T[(kk + 1) * 128 + oo], s);
            s = fmaf(c4.z, v2T[(kk + 2) * 128 + oo], s);
            s = fmaf(c4.w, v2T[(kk + 3) * 128 + oo], s);
        }
        out[(size_t)(b0 + r) * 128 + oo] = s;
    }
}

// ================================================================ launch
extern "C" void kernel_launch(void* const* d_in, const int* in_sizes, int n_in,
                              void* d_out, int out_size, void* d_ws, size_t ws_size,
                              hipStream_t stream) {
    const float* bitplanes  = (const float*)d_in[0];
    const float* conv1_w    = (const float*)d_in[1];
    const float* conv1_b    = (const float*)d_in[2];
    const float* conv2_w    = (const float*)d_in[3];
    const float* conv2_b    = (const float*)d_in[4];
    const float* in_proj_w  = (const float*)d_in[5];
    const float* in_proj_b  = (const float*)d_in[6];
    const float* out_proj_w = (const float*)d_in[7];
    const float* out_proj_b = (const float*)d_in[8];
    const float* ln1_g      = (const float*)d_in[9];
    const float* ln1_b      = (const float*)d_in[10];
    const float* ff1_w      = (const float*)d_in[11];
    const float* ff1_b      = (const float*)d_in[12];
    const float* ff2_w      = (const float*)d_in[13];
    const float* ff2_b      = (const float*)d_in[14];
    const float* ln2_g      = (const float*)d_in[15];
    const float* ln2_b      = (const float*)d_in[16];
    const float* be1_w      = (const float*)d_in[17];
    const float* be1_b      = (const float*)d_in[18];
    const float* be2_w      = (const float*)d_in[19];
    const float* be2_b      = (const float*)d_in[20];
    const float* L1_w       = (const float*)d_in[21];
    const float* L1_b       = (const float*)d_in[22];
    const float* L2_w       = (const float*)d_in[23];
    const float* L2_b       = (const float*)d_in[24];
    const float* Lln_g      = (const float*)d_in[25];
    const float* Lln_b      = (const float*)d_in[26];
    const float* H1_w       = (const float*)d_in[27];
    const float* H1_b       = (const float*)d_in[28];
    const float* H2_w       = (const float*)d_in[29];
    const float* H2_b       = (const float*)d_in[30];
    const float* Hln_g      = (const float*)d_in[31];
    const float* Hln_b      = (const float*)d_in[32];
    const float* v1_w       = (const float*)d_in[33];
    const float* v1_b       = (const float*)d_in[34];
    const float* v2_w       = (const float*)d_in[35];
    const float* v2_b       = (const float*)d_in[36];

    // per-chunk floats = CB*106880; persistent tail = 9,404,416 floats
    const size_t persist = 9404416ull;
    int CB = 64;
    for (int c = 2048; c >= 64; c >>= 1) {
        size_t needBytes = ((size_t)c * 106880ull + persist) * 4ull;
        if (needBytes <= ws_size) { CB = c; break; }
    }
    const int NCH = 2048 / CB;

    float* ws = (float*)d_ws;
    float* a1buf = ws;                                  // CB*16384 fp32
    float* xbuf  = a1buf + (size_t)CB * 16384;          // CB*16384 fp32
    float* sbuf  = xbuf + (size_t)CB * 16384;           // CB*24576 fl = 3 bf16 planes CB*64*256
    float* tbuf  = sbuf + (size_t)CB * 24576;           // CB*49152 fl (qkv fp32 / ff1 planes / be1 parts)
    float* bemf  = tbuf + (size_t)CB * 49152;           // CB*384 fl = 3 bf16 planes CB*256
    float* wpQf  = bemf + (size_t)CB * 384;             // 294,912 (in_proj 3-term pack)
    float* v2T   = wpQf + 294912;                       // 32,768
    float* L1Pf  = v2T + 32768;                         // 294,912
    float* L2Pf  = L1Pf + 294912;                       // 98,304
    float* H1Pf  = L2Pf + 98304;                        // 196,608
    float* H2Pf  = H1Pf + 196608;                       // 98,304
    float* v1Pf  = H2Pf + 98304;                        // 98,304
    float* beB   = v1Pf + 98304;                        // 524,288
    float* wpOf  = beB + 524288;                        // 98,304
    float* wpF1f = wpOf + 98304;                        // 196,608
    float* wpF2f = wpF1f + 196608;                      // 196,608
    float* wpB1f = wpF2f + 196608;                      // 6,291,456
    float* wpB2f = wpB1f + 6291456;                     // 98,304
    float* wpC2f = wpB2f + 98304;                       // 884,736

    unsigned short* soh = (unsigned short*)sbuf;
    unsigned short* som = soh + (size_t)CB * 16384;
    unsigned short* sol = som + (size_t)CB * 16384;
    unsigned short* tbh = (unsigned short*)tbuf;
    unsigned short* tbm = tbh + (size_t)CB * 32768;
    unsigned short* tbl = tbm + (size_t)CB * 32768;
    unsigned short* bemh = (unsigned short*)bemf;
    unsigned short* bemm = bemh + (size_t)CB * 256;
    unsigned short* beml = bemm + (size_t)CB * 256;
    unsigned short* wpQ = (unsigned short*)wpQf;
    unsigned short* L1P = (unsigned short*)L1Pf;
    unsigned short* L2P = (unsigned short*)L2Pf;
    unsigned short* H1P = (unsigned short*)H1Pf;
    unsigned short* H2P = (unsigned short*)H2Pf;
    unsigned short* v1P = (unsigned short*)v1Pf;
    unsigned short* wpO = (unsigned short*)wpOf;
    unsigned short* wpF1 = (unsigned short*)wpF1f;
    unsigned short* wpF2 = (unsigned short*)wpF2f;
    unsigned short* wpB1 = (unsigned short*)wpB1f;
    unsigned short* wpB2 = (unsigned short*)wpB2f;
    unsigned short* wpC2 = (unsigned short*)wpC2f;

    // weight prep (once) — all packs 3-term
    k_tpose<<<64, 256, 0, stream>>>(v2_w, v2T, 128, 256);
    k_wpack3<<<96, 256, 0, stream>>>(in_proj_w, wpQ, 256, 48, 256, 1, 0);
    k_wpack3<<<96, 256, 0, stream>>>(L1_w, L1P, 768, 16, 768, 1, 0);
    k_wpack3<<<32, 256, 0, stream>>>(L2_w, L2P, 256, 16, 256, 1, 0);
    k_wpack3<<<64, 256, 0, stream>>>(H1_w, H1P, 512, 16, 512, 1, 0);
    k_wpack3<<<32, 256, 0, stream>>>(H2_w, H2P, 256, 16, 256, 1, 0);
    k_wpack3<<<32, 256, 0, stream>>>(v1_w, v1P, 256, 16, 256, 1, 0);
    k_wpack3<<<32, 256, 0, stream>>>(out_proj_w, wpO, 256, 16, 256, 1, 0);
    k_wpack3<<<64, 256, 0, stream>>>(ff1_w, wpF1, 256, 32, 256, 1, 0);
    k_wpack3<<<64, 256, 0, stream>>>(ff2_w, wpF2, 512, 16, 512, 1, 0);
    k_wpack3<<<2048, 256, 0, stream>>>(be1_w, wpB1, 16384, 16, 16384, 1, 0);
    k_wpack3<<<32, 256, 0, stream>>>(be2_w, wpB2, 256, 16, 256, 1, 0);
    for (int tap = 0; tap < 9; ++tap)
        k_wpack3<<<32, 256, 0, stream>>>(conv2_w, wpC2 + (size_t)tap * 196608, 256, 16, 2304, 9, tap);

    for (int ch = 0; ch < NCH; ++ch) {
        const float* bp_c = bitplanes + (size_t)ch * CB * 20 * 64;
        // conv encoder (conv2 emits x fp32 + split planes)
        k_conv1<<<CB, 256, 0, stream>>>(bp_c, conv1_w, conv1_b, a1buf);
        k_conv2mf<<<CB, 256, 0, stream>>>(a1buf, wpC2, conv2_b, xbuf, soh, som, sol);
        // qkv projection (wide MFMA GEMM) then attention core
        k_gemm_mf128<<<dim3(CB / 2, 12), 256, 0, stream>>>(soh, som, sol, wpQ, in_proj_b,
                                                           tbuf, nullptr, nullptr, nullptr,
                                                           CB * 64, 768, 256, 0);
        k_attn2<<<dim3(CB, 4), 512, 0, stream>>>(tbuf, soh, som, sol);
        k_gemm_mf128<<<dim3(CB / 2, 4), 256, 0, stream>>>(soh, som, sol, wpO, out_proj_b,
                                                          a1buf, nullptr, nullptr, nullptr,
                                                          CB * 64, 256, 256, 0);
        k_ln_add<<<CB * 16, 256, 0, stream>>>(xbuf, a1buf, ln1_g, ln1_b, soh, som, sol);
        k_gemm_mf128<<<dim3(CB / 2, 8), 256, 0, stream>>>(soh, som, sol, wpF1, ff1_b,
                                                          nullptr, tbh, tbm, tbl,
                                                          CB * 64, 512, 256, 1);
        k_gemm_mf128<<<dim3(CB / 2, 4), 256, 0, stream>>>(tbh, tbm, tbl, wpF2, ff2_b,
                                                          a1buf, nullptr, nullptr, nullptr,
                                                          CB * 64, 256, 512, 0);
        k_ln_add<<<CB * 16, 256, 0, stream>>>(xbuf, a1buf, ln2_g, ln2_b, soh, som, sol);
        // board embedding: be = relu(relu(xf@be1^T+b)@be2^T+b)
        k_gemm_mf<<<dim3(CB / 64, 4, 8), 256, 0, stream>>>(soh, som, sol, wpB1, nullptr,
                                                           tbuf, nullptr, nullptr, nullptr,
                                                           CB, 256, 16384, 2048, 0);
        k_be1_reduce<<<CB, 256, 0, stream>>>(tbuf, be1_b, bemh, bemm, beml, CB * 256);
        k_gemm_mf<<<dim3(CB / 64, 4, 1), 256, 0, stream>>>(bemh, bemm, beml, wpB2, be2_b,
                                                           beB + (size_t)ch * CB * 256, nullptr, nullptr, nullptr,
                                                           CB, 256, 256, 256, 1);
    }

    // HRM recurrence + head (MFMA, 128 blocks x 16 rows, r14 verified)
    k_hrm<<<128, 512, 0, stream>>>(beB, L1P, L1_b, L2P, L2_b, Lln_g, Lln_b,
                                   H1P, H1_b, H2P, H2_b, Hln_g, Hln_b,
                                   v1P, v1_b, v2T, v2_b, (float*)d_out);
}